// Round 7
// baseline (7712.170 us; speedup 1.0000x reference)
//
#include <hip/hip_runtime.h>
#include <hip/hip_fp16.h>

#define NSWEEP 14

static constexpr int F_  = 10;
static constexpr int BF  = 640;   // B*F
static constexpr int HID = 100;
static constexpr float MU = 512.0f;   // ~lambda_max of Wishart(128,128)

// ---- bitwise-uniform 32-lane butterfly sum -------------------------------
template<int CTRL>
__device__ __forceinline__ float dpp_add(float x) {
    int t = __builtin_amdgcn_update_dpp(0, __float_as_int(x), CTRL, 0xF, 0xF, false);
    return x + __int_as_float(t);
}
__device__ __forceinline__ float reduce32(float x) {
    x = dpp_add<0xB1>(x);    // xor 1
    x = dpp_add<0x4E>(x);    // xor 2
    x = dpp_add<0x141>(x);   // xor 7  (row_half_mirror)
    x = dpp_add<0x140>(x);   // xor 15 (row_mirror)
    int t = __builtin_amdgcn_ds_swizzle(__float_as_int(x), 0x401F);  // xor 16
    return x + __int_as_float(t);
}

// One Jacobi rotation of two group-resident columns (4-elem slices/lane).
// Lane-local except the single pq reduce. Threshold at 1e-28 (guard against
// exact-zero pq only — never skip meaningful rotations; the mu-shift
// compresses relative gaps so an eps-level skip freezes mixing too early).
__device__ __forceinline__ void jrot(float (&P)[4], float (&Q)[4],
                                     float& np, float& nq) {
    float pq = 0.f;
    #pragma unroll
    for (int e = 0; e < 4; ++e) pq = fmaf(P[e], Q[e], pq);
    pq = reduce32(pq);
    const float app = np, aqq = nq;
    if (pq * pq > 1e-28f * app * aqq) {
        const float tau = (aqq - app) / (2.f * pq);
        float t = 1.f / (fabsf(tau) + sqrtf(1.f + tau * tau));
        if (tau < 0.f) t = -t;
        const float c = 1.f / sqrtf(1.f + t * t);
        const float s = t * c;
        #pragma unroll
        for (int e = 0; e < 4; ++e) {
            const float pe = P[e];
            P[e] = fmaf(-s, Q[e], c * pe);
            Q[e] = fmaf(s, pe, c * Q[e]);
        }
        np = fmaf(-t, pq, np);
        nq = fmaf( t, pq, nq);
    }
}

// ---------------- Kernel 1: Gram(+shift) + block-cyclic one-sided Jacobi ---
// 16 groups x 32 lanes; group holds 8 columns (half-blocks T,B of 4) of
// G = (L + MU*I) * Racc; lane holds elements [4l,4l+4) of each. Sweep =
// 3 intra rounds + circle-method tournament on 32 half-blocks (31 moves x
// 4 cross-rounds). Exact norms recomputed after every movement (maintained
// analytically in between). lambda_j = ||g_j|| - MU, v_j = g_j / ||g_j||.
__global__ __launch_bounds__(512, 4)
void eig_kernel(const float* __restrict__ Ain,
                float* __restrict__ e_out,          // [BF][128]
                float* __restrict__ s_out,          // [BF][128]
                __half* __restrict__ V_out)         // [BF][128 cols][128 k] (transposed)
{
    __shared__ float SH[15872];     // A-staging chunk (16KB) / 31 exch slots x 512
    __shared__ int   exi[31];
    __shared__ float key[128], csum[128];
    __shared__ int   idxs[128], rankv[128];

    const int tid = threadIdx.x;
    const int g   = tid >> 5;        // group 0..15
    const int l   = tid & 31;        // lane in group
    const int e0  = 4 * l;           // element slice [e0, e0+4)
    const int m   = blockIdx.x;
    const int bb  = m / F_;
    const int ff  = m % F_;

    float T[4][4], Bc[4][4], nT[4], nB[4];
    unsigned int idxT = (unsigned)(8 * g) * 0x01010101u + 0x03020100u;
    unsigned int idxB = idxT + 0x04040404u;

    // ---- init diag of G = L + MU*I ----
    #pragma unroll
    for (int i = 0; i < 4; ++i)
        #pragma unroll
        for (int e = 0; e < 4; ++e) {
            T[i][e]  = (e0 + e == 8 * g + i)     ? MU : 0.f;
            Bc[i][e] = (e0 + e == 8 * g + 4 + i) ? MU : 0.f;
        }

    // ---- Gram accumulate in 4 chunks of 32 A-rows ----
    {
        const float* Ab = Ain + (size_t)bb * 128 * 128 * F_ + ff;
        for (int c0 = 0; c0 < 128; c0 += 32) {
            for (int t = tid; t < 4096; t += 512)
                SH[t] = Ab[(size_t)((c0 + (t >> 7)) * 128 + (t & 127)) * F_];
            __syncthreads();
            for (int j = 0; j < 32; ++j) {
                const float4 ak = *(const float4*)&SH[j * 128 + e0];
                #pragma unroll
                for (int i = 0; i < 4; ++i) {
                    const float at = SH[j * 128 + 8 * g + i];
                    const float ab = SH[j * 128 + 8 * g + 4 + i];
                    T[i][0]  = fmaf(ak.x, at, T[i][0]);
                    T[i][1]  = fmaf(ak.y, at, T[i][1]);
                    T[i][2]  = fmaf(ak.z, at, T[i][2]);
                    T[i][3]  = fmaf(ak.w, at, T[i][3]);
                    Bc[i][0] = fmaf(ak.x, ab, Bc[i][0]);
                    Bc[i][1] = fmaf(ak.y, ab, Bc[i][1]);
                    Bc[i][2] = fmaf(ak.z, ab, Bc[i][2]);
                    Bc[i][3] = fmaf(ak.w, ab, Bc[i][3]);
                }
            }
            __syncthreads();
        }
    }

    // ---- sweeps ----
    for (int sw = 0; sw < NSWEEP; ++sw) {
        // exact norm recompute at sweep start
        #pragma unroll
        for (int i = 0; i < 4; ++i) {
            float a = 0.f, b = 0.f;
            #pragma unroll
            for (int e = 0; e < 4; ++e) {
                a = fmaf(T[i][e], T[i][e], a);
                b = fmaf(Bc[i][e], Bc[i][e], b);
            }
            nT[i] = reduce32(a);
            nB[i] = reduce32(b);
        }

        // intra-half rounds (6+6 pairs; half-block membership permanent)
        #pragma unroll
        for (int r = 1; r <= 3; ++r) {
            #pragma unroll
            for (int i = 0; i < 4; ++i)
                if (i < (i ^ r)) {
                    jrot(T[i],  T[i ^ r],  nT[i], nT[i ^ r]);
                    jrot(Bc[i], Bc[i ^ r], nB[i], nB[i ^ r]);
                }
        }

        // 31 co-residencies (circle method on 32 half-blocks, T0 fixed)
        for (int br = 0; br < 31; ++br) {
            #pragma unroll
            for (int j = 0; j < 4; ++j) {
                #pragma unroll
                for (int i = 0; i < 4; ++i)
                    jrot(T[i], Bc[(i + j) & 3], nT[i], nB[(i + j) & 3]);
            }
            // movement: slot s (1..31) at SH[(s-1)*512]; cycle
            // T1->..->T15->B15->..->B0->T1, T0 fixed.
            if (g > 0) {
                float* base = SH + (g - 1) * 512 + e0;
                #pragma unroll
                for (int i = 0; i < 4; ++i)
                    *(float4*)(base + i * 128) =
                        make_float4(T[i][0], T[i][1], T[i][2], T[i][3]);
                if (l == 0) exi[g - 1] = (int)idxT;
            }
            {
                float* base = SH + (30 - g) * 512 + e0;
                #pragma unroll
                for (int i = 0; i < 4; ++i)
                    *(float4*)(base + i * 128) =
                        make_float4(Bc[i][0], Bc[i][1], Bc[i][2], Bc[i][3]);
                if (l == 0) exi[30 - g] = (int)idxB;
            }
            __syncthreads();
            if (g > 0) {
                const int st = (g >= 2) ? (g - 2) : 30;   // prev slot base
                const float* base = SH + st * 512 + e0;
                #pragma unroll
                for (int i = 0; i < 4; ++i) {
                    const float4 v = *(const float4*)(base + i * 128);
                    T[i][0] = v.x; T[i][1] = v.y; T[i][2] = v.z; T[i][3] = v.w;
                }
                idxT = (unsigned)exi[st];
            }
            {
                const int st = 29 - g;
                const float* base = SH + st * 512 + e0;
                #pragma unroll
                for (int i = 0; i < 4; ++i) {
                    const float4 v = *(const float4*)(base + i * 128);
                    Bc[i][0] = v.x; Bc[i][1] = v.y; Bc[i][2] = v.z; Bc[i][3] = v.w;
                }
                idxB = (unsigned)exi[st];
            }
            __syncthreads();
            // exact norm recompute after movement (kills maintained-norm drift)
            #pragma unroll
            for (int i = 0; i < 4; ++i) {
                float a = 0.f, b = 0.f;
                #pragma unroll
                for (int e = 0; e < 4; ++e) {
                    a = fmaf(T[i][e], T[i][e], a);
                    b = fmaf(Bc[i][e], Bc[i][e], b);
                }
                nT[i] = reduce32(a);
                nB[i] = reduce32(b);
            }
        }
    }

    // ---- epilogue ----
    float invT[4], invB[4];
    #pragma unroll
    for (int i = 0; i < 4; ++i) {
        float a = 0.f, csa = 0.f, b = 0.f, csb = 0.f;
        #pragma unroll
        for (int e = 0; e < 4; ++e) {
            a = fmaf(T[i][e], T[i][e], a);    csa += T[i][e];
            b = fmaf(Bc[i][e], Bc[i][e], b);  csb += Bc[i][e];
        }
        a = reduce32(a); csa = reduce32(csa);
        b = reduce32(b); csb = reduce32(csb);
        invT[i] = 1.f / sqrtf(a);
        invB[i] = 1.f / sqrtf(b);
        if (l == 0) {
            const int ct = (idxT >> (8 * i)) & 0xFF;
            const int cb = (idxB >> (8 * i)) & 0xFF;
            key[ct] = a;  csum[ct] = csa * invT[i] * (1.f / 128.f);
            key[cb] = b;  csum[cb] = csb * invB[i] * (1.f / 128.f);
        }
    }
    __syncthreads();
    if (tid < 128) idxs[tid] = tid;
    __syncthreads();
    for (int kk = 2; kk <= 128; kk <<= 1) {
        for (int jj = kk >> 1; jj > 0; jj >>= 1) {
            if (tid < 128) {
                const int i = tid, l2 = i ^ jj;
                if (l2 > i) {
                    const bool up = ((i & kk) == 0);
                    const float ki = key[i], kl = key[l2];
                    if ((ki > kl) == up) {
                        const int ii = idxs[i], il = idxs[l2];
                        key[i] = kl; key[l2] = ki;
                        idxs[i] = il; idxs[l2] = ii;
                    }
                }
            }
            __syncthreads();
        }
    }
    if (tid < 128) rankv[idxs[tid]] = tid;
    __syncthreads();
    if (tid < 128) {
        e_out[(size_t)m * 128 + tid] = sqrtf(key[tid]) - MU;
        s_out[(size_t)m * 128 + tid] = csum[idxs[tid]];
    }
    {
        __half* Vb = V_out + (size_t)m * 16384;
        #pragma unroll
        for (int i = 0; i < 4; ++i) {
            const int rkT = rankv[(idxT >> (8 * i)) & 0xFF];
            const int rkB = rankv[(idxB >> (8 * i)) & 0xFF];
            __half2 t01 = __floats2half2_rn(T[i][0] * invT[i], T[i][1] * invT[i]);
            __half2 t23 = __floats2half2_rn(T[i][2] * invT[i], T[i][3] * invT[i]);
            __half2 b01 = __floats2half2_rn(Bc[i][0] * invB[i], Bc[i][1] * invB[i]);
            __half2 b23 = __floats2half2_rn(Bc[i][2] * invB[i], Bc[i][3] * invB[i]);
            uint2 ut, ub;
            ut.x = *(unsigned int*)&t01; ut.y = *(unsigned int*)&t23;
            ub.x = *(unsigned int*)&b01; ub.y = *(unsigned int*)&b23;
            *(uint2*)(Vb + rkT * 128 + e0) = ut;
            *(uint2*)(Vb + rkB * 128 + e0) = ub;
        }
    }
}

// ---------------- Kernel 2: MLP on eigenvalues (128 -> 100 -> 100) --------
__global__ __launch_bounds__(128)
void mlp_kernel(const float* __restrict__ e_in,   // [BF][128]
                const float* __restrict__ W0,     // [128][100]
                const float* __restrict__ b0,
                const float* __restrict__ W1,     // [100][100]
                const float* __restrict__ b1,
                float* __restrict__ y_out)        // [BF][100]
{
    __shared__ float ein[128];
    __shared__ float h0[HID];
    const int m = blockIdx.x;
    const int tid = threadIdx.x;
    ein[tid] = e_in[(size_t)m * 128 + tid];
    __syncthreads();
    if (tid < HID) {
        float a = b0[tid];
        for (int i = 0; i < 128; ++i) a += ein[i] * W0[i * HID + tid];
        h0[tid] = fmaxf(a, 0.f);
    }
    __syncthreads();
    if (tid < HID) {
        float a = b1[tid];
        for (int h = 0; h < HID; ++h) a += h0[h] * W1[h * HID + tid];
        y_out[(size_t)m * HID + tid] = fmaxf(a, 0.f);
    }
}

// ---------------- Kernel 3: D = Ysub@W2blk + b2; Out = (D*s)@V^T; exp -----
__global__ __launch_bounds__(256)
void final_kernel(const float* __restrict__ y,     // [BF][100]
                  const float* __restrict__ W2,    // [100][16384]
                  const float* __restrict__ b2,    // [16384]
                  const float* __restrict__ s_in,  // [BF][128]
                  const __half* __restrict__ V_in, // [BF][128 cols][128 k] transposed
                  float* __restrict__ outp)        // [BF][128][128]
{
    extern __shared__ float lds[];
    float* Vs  = lds;            // [128][129] Vs[k][col] (filled in phase 2)
    float* Wm  = lds + 16512;    // [128][129]
    float* Ys  = lds;            // [128][101] staging (overlaps Vs)
    float* W2s = lds + 12928;    // [100][128] staging (overlaps Vs/Wm)

    const int m    = blockIdx.x;
    const int m_hi = m >> 7, m_lo = m & 127;
    const int tid  = threadIdx.x;
    const int tx   = tid & 15, ty = tid >> 4;

    for (int u = tid; u < 128 * 100; u += 256) {
        const int t = u / 100, h = u - t * 100;
        Ys[t * 101 + h] = y[(size_t)(5 * t + m_hi) * 100 + h];
    }
    for (int u = tid; u < 100 * 128; u += 256) {
        const int h = u >> 7, c = u & 127;
        W2s[h * 128 + c] = W2[(size_t)h * 16384 + (size_t)m_lo * 128 + c];
    }
    __syncthreads();

    float acc[8][8];
    #pragma unroll
    for (int a = 0; a < 8; ++a)
        #pragma unroll
        for (int c = 0; c < 8; ++c) acc[a][c] = 0.f;
    for (int h = 0; h < 100; ++h) {
        float yv[8], wv[8];
        #pragma unroll
        for (int a = 0; a < 8; ++a) yv[a] = Ys[(ty + 16 * a) * 101 + h];
        #pragma unroll
        for (int c = 0; c < 8; ++c) wv[c] = W2s[h * 128 + tx + 16 * c];
        #pragma unroll
        for (int a = 0; a < 8; ++a)
            #pragma unroll
            for (int c = 0; c < 8; ++c) acc[a][c] += yv[a] * wv[c];
    }
    {
        float b2v[8], sv[8];
        #pragma unroll
        for (int c = 0; c < 8; ++c) {
            b2v[c] = b2[m_lo * 128 + tx + 16 * c];
            sv[c]  = s_in[(size_t)m * 128 + tx + 16 * c];
        }
        #pragma unroll
        for (int a = 0; a < 8; ++a)
            #pragma unroll
            for (int c = 0; c < 8; ++c)
                acc[a][c] = (acc[a][c] + b2v[c]) * sv[c];
    }
    __syncthreads();

    #pragma unroll
    for (int a = 0; a < 8; ++a)
        #pragma unroll
        for (int c = 0; c < 8; ++c)
            Wm[(ty + 16 * a) * 129 + tx + 16 * c] = acc[a][c];
    for (int u = tid; u < 16384; u += 256) {
        const int colj = u >> 7, k = u & 127;
        Vs[k * 129 + colj] = __half2float(V_in[(size_t)m * 16384 + u]);
    }
    __syncthreads();

    float o[8][8];
    #pragma unroll
    for (int a = 0; a < 8; ++a)
        #pragma unroll
        for (int c = 0; c < 8; ++c) o[a][c] = 0.f;
    for (int j = 0; j < 128; ++j) {
        float wv[8], vv[8];
        #pragma unroll
        for (int a = 0; a < 8; ++a) wv[a] = Wm[(ty + 16 * a) * 129 + j];
        #pragma unroll
        for (int c = 0; c < 8; ++c) vv[c] = Vs[(tx + 16 * c) * 129 + j];
        #pragma unroll
        for (int a = 0; a < 8; ++a)
            #pragma unroll
            for (int c = 0; c < 8; ++c) o[a][c] += wv[a] * vv[c];
    }
    #pragma unroll
    for (int a = 0; a < 8; ++a) {
        const int t = ty + 16 * a;
        const size_t rowbase = (size_t)(5 * t + m_hi) * 16384 + (size_t)m_lo * 128;
        #pragma unroll
        for (int c = 0; c < 8; ++c)
            outp[rowbase + tx + 16 * c] = expf(o[a][c]);
    }
}

// ---------------------------------------------------------------------------
extern "C" void kernel_launch(void* const* d_in, const int* in_sizes, int n_in,
                              void* d_out, int out_size, void* d_ws, size_t ws_size,
                              hipStream_t stream)
{
    const float* Ain = (const float*)d_in[0];
    const float* W0  = (const float*)d_in[1];
    const float* b0  = (const float*)d_in[2];
    const float* W1  = (const float*)d_in[3];
    const float* b1  = (const float*)d_in[4];
    const float* W2  = (const float*)d_in[5];
    const float* b2  = (const float*)d_in[6];
    float* outp = (float*)d_out;

    char* ws = (char*)d_ws;
    __half* Vh  = (__half*)ws;                               // 640*16384*2 = 20971520 B
    float* e_ws = (float*)(ws + 20971520);                   // 640*128*4
    float* s_ws = (float*)(ws + 20971520 + 327680);          // 640*128*4
    float* y_ws = (float*)(ws + 20971520 + 655360);          // 640*100*4

    const size_t lds_bytes = (size_t)(2 * 128 * 129) * sizeof(float); // 132096

    eig_kernel<<<dim3(BF), dim3(512), 0, stream>>>(Ain, e_ws, s_ws, Vh);
    mlp_kernel<<<dim3(BF), dim3(128), 0, stream>>>(e_ws, W0, b0, W1, b1, y_ws);
    final_kernel<<<dim3(BF), dim3(256), lds_bytes, stream>>>(y_ws, W2, b2, s_ws, Vh, outp);
}

// Round 8
// 3760.128 us; speedup vs baseline: 2.0510x; 2.0510x over previous
//
#include <hip/hip_runtime.h>
#include <hip/hip_fp16.h>

#define NSWEEP 12

static constexpr int F_  = 10;
static constexpr int BF  = 640;   // B*F
static constexpr int HID = 100;
static constexpr float MU = 512.0f;   // ~lambda_max of Wishart(128,128)

// ---- bitwise-uniform 32-lane butterfly sum -------------------------------
template<int CTRL>
__device__ __forceinline__ float dpp_add(float x) {
    int t = __builtin_amdgcn_update_dpp(0, __float_as_int(x), CTRL, 0xF, 0xF, false);
    return x + __int_as_float(t);
}
__device__ __forceinline__ float reduce32(float x) {
    x = dpp_add<0xB1>(x);    // xor 1
    x = dpp_add<0x4E>(x);    // xor 2
    x = dpp_add<0x141>(x);   // xor 7  (row_half_mirror)
    x = dpp_add<0x140>(x);   // xor 15 (row_mirror)
    int t = __builtin_amdgcn_ds_swizzle(__float_as_int(x), 0x401F);  // xor 16
    return x + __int_as_float(t);
}

// One Jacobi rotation of two group-resident columns (4-elem slices/lane).
// Lane-local except the single pq reduce. Threshold 1e-28 = guard against
// exact-zero pq only (round-6 lesson: never skip meaningful rotations).
// Scalar chain uses HW rcp/rsq (~1 ulp): rotation orthogonality error
// ~2e-7/rotation, self-correcting; norms recomputed exactly per movement.
__device__ __forceinline__ void jrot(float (&P)[4], float (&Q)[4],
                                     float& np, float& nq) {
    float pq = 0.f;
    #pragma unroll
    for (int e = 0; e < 4; ++e) pq = fmaf(P[e], Q[e], pq);
    pq = reduce32(pq);
    if (pq * pq > 1e-28f * np * nq) {
        const float tau = (nq - np) * 0.5f * __builtin_amdgcn_rcpf(pq);
        const float r   = __builtin_amdgcn_sqrtf(fmaf(tau, tau, 1.f));
        // t = sign(tau)/(|tau|+r) == 1/(tau + copysign(r, tau))
        const float t   = __builtin_amdgcn_rcpf(tau + copysignf(r, tau));
        const float c   = __builtin_amdgcn_rsqf(fmaf(t, t, 1.f));
        const float s   = t * c;
        #pragma unroll
        for (int e = 0; e < 4; ++e) {
            const float pe = P[e];
            P[e] = fmaf(-s, Q[e], c * pe);
            Q[e] = fmaf(s, pe, c * Q[e]);
        }
        np = fmaf(-t, pq, np);
        nq = fmaf( t, pq, nq);
    }
}

// ---------------- Kernel 1: Gram(+shift) + block-cyclic one-sided Jacobi ---
// 16 groups x 32 lanes; group holds 8 columns (half-blocks T,B of 4) of
// G = (L + MU*I) * Racc; lane holds elements [4l,4l+4) of each. Sweep =
// 3 intra rounds + circle-method tournament on 32 half-blocks (31 moves x
// 4 cross-rounds). Exact norms recomputed after every movement (maintained
// analytically in between). lambda_j = ||g_j|| - MU, v_j = g_j / ||g_j||.
__global__ __launch_bounds__(512, 4)
void eig_kernel(const float* __restrict__ Ain,
                float* __restrict__ e_out,          // [BF][128]
                float* __restrict__ s_out,          // [BF][128]
                __half* __restrict__ V_out)         // [BF][128 cols][128 k] (transposed)
{
    __shared__ float SH[15872];     // A-staging chunk (16KB) / 31 exch slots x 512
    __shared__ int   exi[31];
    __shared__ float key[128], csum[128];
    __shared__ int   idxs[128], rankv[128];

    const int tid = threadIdx.x;
    const int g   = tid >> 5;        // group 0..15
    const int l   = tid & 31;        // lane in group
    const int e0  = 4 * l;           // element slice [e0, e0+4)
    const int m   = blockIdx.x;
    const int bb  = m / F_;
    const int ff  = m % F_;

    float T[4][4], Bc[4][4], nT[4], nB[4];
    unsigned int idxT = (unsigned)(8 * g) * 0x01010101u + 0x03020100u;
    unsigned int idxB = idxT + 0x04040404u;

    // ---- init diag of G = L + MU*I ----
    #pragma unroll
    for (int i = 0; i < 4; ++i)
        #pragma unroll
        for (int e = 0; e < 4; ++e) {
            T[i][e]  = (e0 + e == 8 * g + i)     ? MU : 0.f;
            Bc[i][e] = (e0 + e == 8 * g + 4 + i) ? MU : 0.f;
        }

    // ---- Gram accumulate in 4 chunks of 32 A-rows ----
    {
        const float* Ab = Ain + (size_t)bb * 128 * 128 * F_ + ff;
        for (int c0 = 0; c0 < 128; c0 += 32) {
            for (int t = tid; t < 4096; t += 512)
                SH[t] = Ab[(size_t)((c0 + (t >> 7)) * 128 + (t & 127)) * F_];
            __syncthreads();
            for (int j = 0; j < 32; ++j) {
                const float4 ak = *(const float4*)&SH[j * 128 + e0];
                #pragma unroll
                for (int i = 0; i < 4; ++i) {
                    const float at = SH[j * 128 + 8 * g + i];
                    const float ab = SH[j * 128 + 8 * g + 4 + i];
                    T[i][0]  = fmaf(ak.x, at, T[i][0]);
                    T[i][1]  = fmaf(ak.y, at, T[i][1]);
                    T[i][2]  = fmaf(ak.z, at, T[i][2]);
                    T[i][3]  = fmaf(ak.w, at, T[i][3]);
                    Bc[i][0] = fmaf(ak.x, ab, Bc[i][0]);
                    Bc[i][1] = fmaf(ak.y, ab, Bc[i][1]);
                    Bc[i][2] = fmaf(ak.z, ab, Bc[i][2]);
                    Bc[i][3] = fmaf(ak.w, ab, Bc[i][3]);
                }
            }
            __syncthreads();
        }
    }

    // ---- sweeps ----
    for (int sw = 0; sw < NSWEEP; ++sw) {
        // exact norm recompute at sweep start
        #pragma unroll
        for (int i = 0; i < 4; ++i) {
            float a = 0.f, b = 0.f;
            #pragma unroll
            for (int e = 0; e < 4; ++e) {
                a = fmaf(T[i][e], T[i][e], a);
                b = fmaf(Bc[i][e], Bc[i][e], b);
            }
            nT[i] = reduce32(a);
            nB[i] = reduce32(b);
        }

        // intra-half rounds (6+6 pairs; half-block membership permanent)
        #pragma unroll
        for (int r = 1; r <= 3; ++r) {
            #pragma unroll
            for (int i = 0; i < 4; ++i)
                if (i < (i ^ r)) {
                    jrot(T[i],  T[i ^ r],  nT[i], nT[i ^ r]);
                    jrot(Bc[i], Bc[i ^ r], nB[i], nB[i ^ r]);
                }
        }

        // 31 co-residencies (circle method on 32 half-blocks, T0 fixed)
        for (int br = 0; br < 31; ++br) {
            #pragma unroll
            for (int j = 0; j < 4; ++j) {
                #pragma unroll
                for (int i = 0; i < 4; ++i)
                    jrot(T[i], Bc[(i + j) & 3], nT[i], nB[(i + j) & 3]);
            }
            // movement: slot s (1..31) at SH[(s-1)*512]; cycle
            // T1->..->T15->B15->..->B0->T1, T0 fixed.
            if (g > 0) {
                float* base = SH + (g - 1) * 512 + e0;
                #pragma unroll
                for (int i = 0; i < 4; ++i)
                    *(float4*)(base + i * 128) =
                        make_float4(T[i][0], T[i][1], T[i][2], T[i][3]);
                if (l == 0) exi[g - 1] = (int)idxT;
            }
            {
                float* base = SH + (30 - g) * 512 + e0;
                #pragma unroll
                for (int i = 0; i < 4; ++i)
                    *(float4*)(base + i * 128) =
                        make_float4(Bc[i][0], Bc[i][1], Bc[i][2], Bc[i][3]);
                if (l == 0) exi[30 - g] = (int)idxB;
            }
            __syncthreads();
            if (g > 0) {
                const int st = (g >= 2) ? (g - 2) : 30;   // prev slot base
                const float* base = SH + st * 512 + e0;
                #pragma unroll
                for (int i = 0; i < 4; ++i) {
                    const float4 v = *(const float4*)(base + i * 128);
                    T[i][0] = v.x; T[i][1] = v.y; T[i][2] = v.z; T[i][3] = v.w;
                }
                idxT = (unsigned)exi[st];
            }
            {
                const int st = 29 - g;
                const float* base = SH + st * 512 + e0;
                #pragma unroll
                for (int i = 0; i < 4; ++i) {
                    const float4 v = *(const float4*)(base + i * 128);
                    Bc[i][0] = v.x; Bc[i][1] = v.y; Bc[i][2] = v.z; Bc[i][3] = v.w;
                }
                idxB = (unsigned)exi[st];
            }
            __syncthreads();
            // exact norm recompute after movement (kills maintained-norm drift)
            #pragma unroll
            for (int i = 0; i < 4; ++i) {
                float a = 0.f, b = 0.f;
                #pragma unroll
                for (int e = 0; e < 4; ++e) {
                    a = fmaf(T[i][e], T[i][e], a);
                    b = fmaf(Bc[i][e], Bc[i][e], b);
                }
                nT[i] = reduce32(a);
                nB[i] = reduce32(b);
            }
        }
    }

    // ---- epilogue ----
    float invT[4], invB[4];
    #pragma unroll
    for (int i = 0; i < 4; ++i) {
        float a = 0.f, csa = 0.f, b = 0.f, csb = 0.f;
        #pragma unroll
        for (int e = 0; e < 4; ++e) {
            a = fmaf(T[i][e], T[i][e], a);    csa += T[i][e];
            b = fmaf(Bc[i][e], Bc[i][e], b);  csb += Bc[i][e];
        }
        a = reduce32(a); csa = reduce32(csa);
        b = reduce32(b); csb = reduce32(csb);
        invT[i] = 1.f / sqrtf(a);
        invB[i] = 1.f / sqrtf(b);
        if (l == 0) {
            const int ct = (idxT >> (8 * i)) & 0xFF;
            const int cb = (idxB >> (8 * i)) & 0xFF;
            key[ct] = a;  csum[ct] = csa * invT[i] * (1.f / 128.f);
            key[cb] = b;  csum[cb] = csb * invB[i] * (1.f / 128.f);
        }
    }
    __syncthreads();
    if (tid < 128) idxs[tid] = tid;
    __syncthreads();
    for (int kk = 2; kk <= 128; kk <<= 1) {
        for (int jj = kk >> 1; jj > 0; jj >>= 1) {
            if (tid < 128) {
                const int i = tid, l2 = i ^ jj;
                if (l2 > i) {
                    const bool up = ((i & kk) == 0);
                    const float ki = key[i], kl = key[l2];
                    if ((ki > kl) == up) {
                        const int ii = idxs[i], il = idxs[l2];
                        key[i] = kl; key[l2] = ki;
                        idxs[i] = il; idxs[l2] = ii;
                    }
                }
            }
            __syncthreads();
        }
    }
    if (tid < 128) rankv[idxs[tid]] = tid;
    __syncthreads();
    if (tid < 128) {
        e_out[(size_t)m * 128 + tid] = sqrtf(key[tid]) - MU;
        s_out[(size_t)m * 128 + tid] = csum[idxs[tid]];
    }
    {
        __half* Vb = V_out + (size_t)m * 16384;
        #pragma unroll
        for (int i = 0; i < 4; ++i) {
            const int rkT = rankv[(idxT >> (8 * i)) & 0xFF];
            const int rkB = rankv[(idxB >> (8 * i)) & 0xFF];
            __half2 t01 = __floats2half2_rn(T[i][0] * invT[i], T[i][1] * invT[i]);
            __half2 t23 = __floats2half2_rn(T[i][2] * invT[i], T[i][3] * invT[i]);
            __half2 b01 = __floats2half2_rn(Bc[i][0] * invB[i], Bc[i][1] * invB[i]);
            __half2 b23 = __floats2half2_rn(Bc[i][2] * invB[i], Bc[i][3] * invB[i]);
            uint2 ut, ub;
            ut.x = *(unsigned int*)&t01; ut.y = *(unsigned int*)&t23;
            ub.x = *(unsigned int*)&b01; ub.y = *(unsigned int*)&b23;
            *(uint2*)(Vb + rkT * 128 + e0) = ut;
            *(uint2*)(Vb + rkB * 128 + e0) = ub;
        }
    }
}

// ---------------- Kernel 2: MLP on eigenvalues (128 -> 100 -> 100) --------
__global__ __launch_bounds__(128)
void mlp_kernel(const float* __restrict__ e_in,   // [BF][128]
                const float* __restrict__ W0,     // [128][100]
                const float* __restrict__ b0,
                const float* __restrict__ W1,     // [100][100]
                const float* __restrict__ b1,
                float* __restrict__ y_out)        // [BF][100]
{
    __shared__ float ein[128];
    __shared__ float h0[HID];
    const int m = blockIdx.x;
    const int tid = threadIdx.x;
    ein[tid] = e_in[(size_t)m * 128 + tid];
    __syncthreads();
    if (tid < HID) {
        float a = b0[tid];
        for (int i = 0; i < 128; ++i) a += ein[i] * W0[i * HID + tid];
        h0[tid] = fmaxf(a, 0.f);
    }
    __syncthreads();
    if (tid < HID) {
        float a = b1[tid];
        for (int h = 0; h < HID; ++h) a += h0[h] * W1[h * HID + tid];
        y_out[(size_t)m * HID + tid] = fmaxf(a, 0.f);
    }
}

// ---------------- Kernel 3: D = Ysub@W2blk + b2; Out = (D*s)@V^T; exp -----
__global__ __launch_bounds__(256)
void final_kernel(const float* __restrict__ y,     // [BF][100]
                  const float* __restrict__ W2,    // [100][16384]
                  const float* __restrict__ b2,    // [16384]
                  const float* __restrict__ s_in,  // [BF][128]
                  const __half* __restrict__ V_in, // [BF][128 cols][128 k] transposed
                  float* __restrict__ outp)        // [BF][128][128]
{
    extern __shared__ float lds[];
    float* Vs  = lds;            // [128][129] Vs[k][col] (filled in phase 2)
    float* Wm  = lds + 16512;    // [128][129]
    float* Ys  = lds;            // [128][101] staging (overlaps Vs)
    float* W2s = lds + 12928;    // [100][128] staging (overlaps Vs/Wm)

    const int m    = blockIdx.x;
    const int m_hi = m >> 7, m_lo = m & 127;
    const int tid  = threadIdx.x;
    const int tx   = tid & 15, ty = tid >> 4;

    for (int u = tid; u < 128 * 100; u += 256) {
        const int t = u / 100, h = u - t * 100;
        Ys[t * 101 + h] = y[(size_t)(5 * t + m_hi) * 100 + h];
    }
    for (int u = tid; u < 100 * 128; u += 256) {
        const int h = u >> 7, c = u & 127;
        W2s[h * 128 + c] = W2[(size_t)h * 16384 + (size_t)m_lo * 128 + c];
    }
    __syncthreads();

    float acc[8][8];
    #pragma unroll
    for (int a = 0; a < 8; ++a)
        #pragma unroll
        for (int c = 0; c < 8; ++c) acc[a][c] = 0.f;
    for (int h = 0; h < 100; ++h) {
        float yv[8], wv[8];
        #pragma unroll
        for (int a = 0; a < 8; ++a) yv[a] = Ys[(ty + 16 * a) * 101 + h];
        #pragma unroll
        for (int c = 0; c < 8; ++c) wv[c] = W2s[h * 128 + tx + 16 * c];
        #pragma unroll
        for (int a = 0; a < 8; ++a)
            #pragma unroll
            for (int c = 0; c < 8; ++c) acc[a][c] += yv[a] * wv[c];
    }
    {
        float b2v[8], sv[8];
        #pragma unroll
        for (int c = 0; c < 8; ++c) {
            b2v[c] = b2[m_lo * 128 + tx + 16 * c];
            sv[c]  = s_in[(size_t)m * 128 + tx + 16 * c];
        }
        #pragma unroll
        for (int a = 0; a < 8; ++a)
            #pragma unroll
            for (int c = 0; c < 8; ++c)
                acc[a][c] = (acc[a][c] + b2v[c]) * sv[c];
    }
    __syncthreads();

    #pragma unroll
    for (int a = 0; a < 8; ++a)
        #pragma unroll
        for (int c = 0; c < 8; ++c)
            Wm[(ty + 16 * a) * 129 + tx + 16 * c] = acc[a][c];
    for (int u = tid; u < 16384; u += 256) {
        const int colj = u >> 7, k = u & 127;
        Vs[k * 129 + colj] = __half2float(V_in[(size_t)m * 16384 + u]);
    }
    __syncthreads();

    float o[8][8];
    #pragma unroll
    for (int a = 0; a < 8; ++a)
        #pragma unroll
        for (int c = 0; c < 8; ++c) o[a][c] = 0.f;
    for (int j = 0; j < 128; ++j) {
        float wv[8], vv[8];
        #pragma unroll
        for (int a = 0; a < 8; ++a) wv[a] = Wm[(ty + 16 * a) * 129 + j];
        #pragma unroll
        for (int c = 0; c < 8; ++c) vv[c] = Vs[(tx + 16 * c) * 129 + j];
        #pragma unroll
        for (int a = 0; a < 8; ++a)
            #pragma unroll
            for (int c = 0; c < 8; ++c) o[a][c] += wv[a] * vv[c];
    }
    #pragma unroll
    for (int a = 0; a < 8; ++a) {
        const int t = ty + 16 * a;
        const size_t rowbase = (size_t)(5 * t + m_hi) * 16384 + (size_t)m_lo * 128;
        #pragma unroll
        for (int c = 0; c < 8; ++c)
            outp[rowbase + tx + 16 * c] = expf(o[a][c]);
    }
}

// ---------------------------------------------------------------------------
extern "C" void kernel_launch(void* const* d_in, const int* in_sizes, int n_in,
                              void* d_out, int out_size, void* d_ws, size_t ws_size,
                              hipStream_t stream)
{
    const float* Ain = (const float*)d_in[0];
    const float* W0  = (const float*)d_in[1];
    const float* b0  = (const float*)d_in[2];
    const float* W1  = (const float*)d_in[3];
    const float* b1  = (const float*)d_in[4];
    const float* W2  = (const float*)d_in[5];
    const float* b2  = (const float*)d_in[6];
    float* outp = (float*)d_out;

    char* ws = (char*)d_ws;
    __half* Vh  = (__half*)ws;                               // 640*16384*2 = 20971520 B
    float* e_ws = (float*)(ws + 20971520);                   // 640*128*4
    float* s_ws = (float*)(ws + 20971520 + 327680);          // 640*128*4
    float* y_ws = (float*)(ws + 20971520 + 655360);          // 640*100*4

    const size_t lds_bytes = (size_t)(2 * 128 * 129) * sizeof(float); // 132096

    eig_kernel<<<dim3(BF), dim3(512), 0, stream>>>(Ain, e_ws, s_ws, Vh);
    mlp_kernel<<<dim3(BF), dim3(128), 0, stream>>>(e_ws, W0, b0, W1, b1, y_ws);
    final_kernel<<<dim3(BF), dim3(256), lds_bytes, stream>>>(y_ws, W2, b2, s_ws, Vh, outp);
}

// Round 9
// 3331.952 us; speedup vs baseline: 2.3146x; 1.1285x over previous
//
#include <hip/hip_runtime.h>
#include <hip/hip_fp16.h>

#define NSWEEP 12

static constexpr int F_  = 10;
static constexpr int BF  = 640;   // B*F
static constexpr int HID = 100;
static constexpr float MU = 512.0f;   // ~lambda_max of Wishart(128,128)

// ---- DPP helpers ----------------------------------------------------------
template<int CTRL>
__device__ __forceinline__ float dpp_add(float x) {
    int t = __builtin_amdgcn_update_dpp(0, __float_as_int(x), CTRL, 0xF, 0xF, false);
    return x + __int_as_float(t);
}
// 8-lane butterfly all-reduce: xor1, xor2, xor7 — pure VALU, bitwise-uniform.
__device__ __forceinline__ float reduce8(float x) {
    x = dpp_add<0xB1>(x);    // xor 1 (quad_perm [1,0,3,2])
    x = dpp_add<0x4E>(x);    // xor 2 (quad_perm [2,3,0,1])
    x = dpp_add<0x141>(x);   // xor 7 (row_half_mirror)
    return x;
}
// lane-xor data movers: xor8 = DPP row_ror:8 (VALU); xor16/24 = ds_swizzle.
__device__ __forceinline__ int mvi(int x, int mode) { return x; }
template<int MODE>
__device__ __forceinline__ int mv_i(int x) {
    if constexpr (MODE == 8)
        return __builtin_amdgcn_update_dpp(0, x, 0x128, 0xF, 0xF, false);
    else if constexpr (MODE == 16)
        return __builtin_amdgcn_ds_swizzle(x, 0x401F);
    else
        return __builtin_amdgcn_ds_swizzle(x, 0x601F);
}
template<int MODE>
__device__ __forceinline__ float mv_f(float x) {
    return __int_as_float(mv_i<MODE>(__float_as_int(x)));
}

__device__ __forceinline__ float rcpf(float x) { return __builtin_amdgcn_rcpf(x); }
__device__ __forceinline__ float rsqf(float x) { return __builtin_amdgcn_rsqf(x); }

// Local Jacobi rotation: both columns resident in this lane (16 elems each).
// One instruction stream serves 4 independent pairs (one per 8-lane subgroup).
__device__ __forceinline__ void jrotL(float (&P)[16], float (&Q)[16],
                                      float& np, float& nq) {
    float d0 = 0.f, d1 = 0.f, d2 = 0.f, d3 = 0.f;
    #pragma unroll
    for (int e = 0; e < 4; ++e) {
        d0 = fmaf(P[e],      Q[e],      d0);
        d1 = fmaf(P[e + 4],  Q[e + 4],  d1);
        d2 = fmaf(P[e + 8],  Q[e + 8],  d2);
        d3 = fmaf(P[e + 12], Q[e + 12], d3);
    }
    const float pq = reduce8((d0 + d1) + (d2 + d3));
    if (pq * pq > 1e-28f * np * nq) {
        const float tau = (nq - np) * 0.5f * rcpf(pq);
        const float r   = __builtin_amdgcn_sqrtf(fmaf(tau, tau, 1.f));
        const float t   = rcpf(tau + copysignf(r, tau));
        const float c   = rsqf(fmaf(t, t, 1.f));
        const float s   = t * c;
        #pragma unroll
        for (int e = 0; e < 16; ++e) {
            const float pe = P[e];
            P[e] = fmaf(-s, Q[e], c * pe);
            Q[e] = fmaf(s, pe, c * Q[e]);
        }
        np = fmaf(-t, pq, np);
        nq = fmaf( t, pq, nq);
    }
}

// Cross-subgroup rotation (intra-half-block rounds): partner column fetched
// via lane-xor; each side updates its own column only.
template<int MODE>
__device__ __forceinline__ void jrotX(float (&P)[16], float& np, const bool isp) {
    float part[16];
    #pragma unroll
    for (int e = 0; e < 16; ++e) part[e] = mv_f<MODE>(P[e]);
    const float npart = mv_f<MODE>(np);
    float d0 = 0.f, d1 = 0.f, d2 = 0.f, d3 = 0.f;
    #pragma unroll
    for (int e = 0; e < 4; ++e) {
        d0 = fmaf(P[e],      part[e],      d0);
        d1 = fmaf(P[e + 4],  part[e + 4],  d1);
        d2 = fmaf(P[e + 8],  part[e + 8],  d2);
        d3 = fmaf(P[e + 12], part[e + 12], d3);
    }
    const float pq  = reduce8((d0 + d1) + (d2 + d3));
    const float app = isp ? np : npart;
    const float aqq = isp ? npart : np;
    if (pq * pq > 1e-28f * app * aqq) {
        const float tau = (aqq - app) * 0.5f * rcpf(pq);
        const float r   = __builtin_amdgcn_sqrtf(fmaf(tau, tau, 1.f));
        const float t   = rcpf(tau + copysignf(r, tau));
        const float c   = rsqf(fmaf(t, t, 1.f));
        const float s   = t * c;
        const float sg_ = isp ? -s : s;
        #pragma unroll
        for (int e = 0; e < 16; ++e)
            P[e] = fmaf(sg_, part[e], c * P[e]);
        np = fmaf(isp ? -t : t, pq, np);
    }
}

// ---------------- Kernel 1: Gram(+shift) + block-cyclic one-sided Jacobi ---
// 16 groups x 32 lanes = 64 subgroups of 8; subgroup sg of group g holds the
// pair (T[sg], B[sg]) entirely (16 elems/lane). Cross rounds pair T[sg] with
// B[sg^x] by physically xor-moving B (DPP for xor8, ds_swizzle for xor24).
// Half-block movement between groups via 16 aliased LDS slots (2 phases).
__global__ __launch_bounds__(512, 4)
void eig_kernel(const float* __restrict__ Ain,
                float* __restrict__ e_out,          // [BF][128]
                float* __restrict__ s_out,          // [BF][128]
                __half* __restrict__ V_out)         // [BF][128 cols][128 k] (transposed)
{
    __shared__ float SH[16 * 512];   // 16 phys slots (32KB); Gram chunk overlaps
    __shared__ int   exid[31][4];
    __shared__ float key[128], csum[128];
    __shared__ int   idxs[128], rankv[128];

    const int tid = threadIdx.x;
    const int g   = tid >> 5;        // group 0..15
    const int l   = tid & 31;        // lane in group
    const int sg  = l >> 3;          // subgroup 0..3
    const int l7  = l & 7;           // lane in subgroup
    const int e0  = l7 * 16;         // element slice [e0, e0+16)
    const int m   = blockIdx.x;
    const int bb  = m / F_;
    const int ff  = m % F_;

    float T[16], Bc[16];
    float nT, nB;
    int idT = 8 * g + sg;
    int idB = idT + 4;

    // ---- init diag of G = L + MU*I ----
    #pragma unroll
    for (int e = 0; e < 16; ++e) {
        T[e]  = (e0 + e == idT) ? MU : 0.f;
        Bc[e] = (e0 + e == idB) ? MU : 0.f;
    }

    // ---- Gram accumulate in 4 chunks of 32 A-rows ----
    {
        const float* Ab = Ain + (size_t)bb * 128 * 128 * F_ + ff;
        for (int c0 = 0; c0 < 128; c0 += 32) {
            for (int t = tid; t < 4096; t += 512)
                SH[t] = Ab[(size_t)((c0 + (t >> 7)) * 128 + (t & 127)) * F_];
            __syncthreads();
            for (int j = 0; j < 32; ++j) {
                const float at = SH[j * 128 + idT];
                const float ab = SH[j * 128 + idB];
                #pragma unroll
                for (int t = 0; t < 4; ++t) {
                    const float4 a = *(const float4*)&SH[j * 128 + e0 + 4 * t];
                    T[4*t+0]  = fmaf(a.x, at, T[4*t+0]);
                    T[4*t+1]  = fmaf(a.y, at, T[4*t+1]);
                    T[4*t+2]  = fmaf(a.z, at, T[4*t+2]);
                    T[4*t+3]  = fmaf(a.w, at, T[4*t+3]);
                    Bc[4*t+0] = fmaf(a.x, ab, Bc[4*t+0]);
                    Bc[4*t+1] = fmaf(a.y, ab, Bc[4*t+1]);
                    Bc[4*t+2] = fmaf(a.z, ab, Bc[4*t+2]);
                    Bc[4*t+3] = fmaf(a.w, ab, Bc[4*t+3]);
                }
            }
            __syncthreads();
        }
    }

    // exact norms
    {
        float a = 0.f, b = 0.f;
        #pragma unroll
        for (int e = 0; e < 16; ++e) {
            a = fmaf(T[e], T[e], a);
            b = fmaf(Bc[e], Bc[e], b);
        }
        nT = reduce8(a); nB = reduce8(b);
    }

    // ---- sweeps ----
    for (int sw = 0; sw < NSWEEP; ++sw) {
        // intra-half rounds: pairs (sg, sg^r) within T and within B
        {
            const bool p1 = sg < (sg ^ 1), p2 = sg < (sg ^ 2), p3 = sg < (sg ^ 3);
            jrotX<8>(T, nT, p1);   jrotX<8>(Bc, nB, p1);
            jrotX<16>(T, nT, p2);  jrotX<16>(Bc, nB, p2);
            jrotX<24>(T, nT, p3);  jrotX<24>(Bc, nB, p3);
        }

        // 31 co-residencies (circle method on 32 half-blocks, T0 fixed)
        for (int br = 0; br < 31; ++br) {
            // x = 0,1,2,3 pairing via B-moves with deltas xor8,xor24,xor8,xor24
            jrotL(T, Bc, nT, nB);
            #pragma unroll
            for (int e = 0; e < 16; ++e) Bc[e] = mv_f<8>(Bc[e]);
            nB = mv_f<8>(nB); idB = mv_i<8>(idB);
            jrotL(T, Bc, nT, nB);
            #pragma unroll
            for (int e = 0; e < 16; ++e) Bc[e] = mv_f<24>(Bc[e]);
            nB = mv_f<24>(nB); idB = mv_i<24>(idB);
            jrotL(T, Bc, nT, nB);
            #pragma unroll
            for (int e = 0; e < 16; ++e) Bc[e] = mv_f<8>(Bc[e]);
            nB = mv_f<8>(nB); idB = mv_i<8>(idB);
            jrotL(T, Bc, nT, nB);
            #pragma unroll
            for (int e = 0; e < 16; ++e) Bc[e] = mv_f<24>(Bc[e]);   // restore
            nB = mv_f<24>(nB); idB = mv_i<24>(idB);

            // ---- half-block movement, slot cycle T1..T15,B15..B0 -> T1 ----
            // 31 logical slots aliased to 16 phys: s<=14 -> s; 29,30 -> 15;
            // 15..28 -> s-15. Phase 1 = T-chain (+seam B0), phase 2 = B-chain.
            if (g > 0) {                               // T_g -> slot g-1
                float* d = &SH[(g - 1) * 512 + sg * 128 + e0];
                #pragma unroll
                for (int t = 0; t < 4; ++t)
                    *(float4*)(d + 4 * t) = make_float4(T[4*t], T[4*t+1], T[4*t+2], T[4*t+3]);
                if (l7 == 0) exid[g - 1][sg] = idT;
            } else {                                   // B_0 -> slot 30 (phys 15)
                float* d = &SH[15 * 512 + sg * 128 + e0];
                #pragma unroll
                for (int t = 0; t < 4; ++t)
                    *(float4*)(d + 4 * t) = make_float4(Bc[4*t], Bc[4*t+1], Bc[4*t+2], Bc[4*t+3]);
                if (l7 == 0) exid[30][sg] = idB;
            }
            __syncthreads();
            if (g >= 1) {                              // T_g <- slot (g==1 ? 30 : g-2)
                const int ph = (g == 1) ? 15 : (g - 2);
                const int sl = (g == 1) ? 30 : (g - 2);
                const float* r = &SH[ph * 512 + sg * 128 + e0];
                #pragma unroll
                for (int t = 0; t < 4; ++t) {
                    const float4 v = *(const float4*)(r + 4 * t);
                    T[4*t] = v.x; T[4*t+1] = v.y; T[4*t+2] = v.z; T[4*t+3] = v.w;
                }
                idT = exid[sl][sg];
            }
            __syncthreads();
            if (g > 0) {                               // B_g -> slot 30-g (15..29)
                const int s = 30 - g;
                const int ph = (s == 29) ? 15 : (s - 15);
                float* d = &SH[ph * 512 + sg * 128 + e0];
                #pragma unroll
                for (int t = 0; t < 4; ++t)
                    *(float4*)(d + 4 * t) = make_float4(Bc[4*t], Bc[4*t+1], Bc[4*t+2], Bc[4*t+3]);
                if (l7 == 0) exid[s][sg] = idB;
            }
            __syncthreads();
            {                                          // B_g <- slot 29-g (29..14)
                const int s = 29 - g;
                const int ph = (s == 29) ? 15 : ((s == 14) ? 14 : (s - 15));
                const float* r = &SH[ph * 512 + sg * 128 + e0];
                #pragma unroll
                for (int t = 0; t < 4; ++t) {
                    const float4 v = *(const float4*)(r + 4 * t);
                    Bc[4*t] = v.x; Bc[4*t+1] = v.y; Bc[4*t+2] = v.z; Bc[4*t+3] = v.w;
                }
                idB = exid[s][sg];
            }
            __syncthreads();
            // exact norm recompute (kills maintained-norm drift)
            {
                float a = 0.f, b = 0.f;
                #pragma unroll
                for (int e = 0; e < 16; ++e) {
                    a = fmaf(T[e], T[e], a);
                    b = fmaf(Bc[e], Bc[e], b);
                }
                nT = reduce8(a); nB = reduce8(b);
            }
        }
    }

    // ---- epilogue ----
    {
        float a = 0.f, ca = 0.f, b = 0.f, cb = 0.f;
        #pragma unroll
        for (int e = 0; e < 16; ++e) {
            a = fmaf(T[e], T[e], a);    ca += T[e];
            b = fmaf(Bc[e], Bc[e], b);  cb += Bc[e];
        }
        a = reduce8(a); ca = reduce8(ca);
        b = reduce8(b); cb = reduce8(cb);
        const float ivT = 1.f / sqrtf(a);
        const float ivB = 1.f / sqrtf(b);
        if (l7 == 0) {
            key[idT] = a;  csum[idT] = ca * ivT * (1.f / 128.f);
            key[idB] = b;  csum[idB] = cb * ivB * (1.f / 128.f);
        }
        __syncthreads();
        if (tid < 128) idxs[tid] = tid;
        __syncthreads();
        for (int kk = 2; kk <= 128; kk <<= 1) {
            for (int jj = kk >> 1; jj > 0; jj >>= 1) {
                if (tid < 128) {
                    const int i = tid, l2 = i ^ jj;
                    if (l2 > i) {
                        const bool up = ((i & kk) == 0);
                        const float ki = key[i], kl = key[l2];
                        if ((ki > kl) == up) {
                            const int ii = idxs[i], il = idxs[l2];
                            key[i] = kl; key[l2] = ki;
                            idxs[i] = il; idxs[l2] = ii;
                        }
                    }
                }
                __syncthreads();
            }
        }
        if (tid < 128) rankv[idxs[tid]] = tid;
        __syncthreads();
        if (tid < 128) {
            e_out[(size_t)m * 128 + tid] = sqrtf(key[tid]) - MU;
            s_out[(size_t)m * 128 + tid] = csum[idxs[tid]];
        }
        __half* Vb = V_out + (size_t)m * 16384;
        const int rkT = rankv[idT], rkB = rankv[idB];
        uint4 u0, u1;
        unsigned int* pu = (unsigned int*)&u0;
        #pragma unroll
        for (int t = 0; t < 8; ++t) {
            __half2 h = __floats2half2_rn(T[2*t] * ivT, T[2*t+1] * ivT);
            ((unsigned int*)&u0)[t & 3] = *(unsigned int*)&h;
            if (t == 3) u1 = u0;
        }
        // (recompute cleanly to avoid aliasing confusion)
        unsigned int wT[8], wB[8];
        #pragma unroll
        for (int t = 0; t < 8; ++t) {
            __half2 hT = __floats2half2_rn(T[2*t] * ivT,  T[2*t+1] * ivT);
            __half2 hB = __floats2half2_rn(Bc[2*t] * ivB, Bc[2*t+1] * ivB);
            wT[t] = *(unsigned int*)&hT;
            wB[t] = *(unsigned int*)&hB;
        }
        *(uint4*)(Vb + rkT * 128 + e0)     = make_uint4(wT[0], wT[1], wT[2], wT[3]);
        *(uint4*)(Vb + rkT * 128 + e0 + 8) = make_uint4(wT[4], wT[5], wT[6], wT[7]);
        *(uint4*)(Vb + rkB * 128 + e0)     = make_uint4(wB[0], wB[1], wB[2], wB[3]);
        *(uint4*)(Vb + rkB * 128 + e0 + 8) = make_uint4(wB[4], wB[5], wB[6], wB[7]);
    }
}

// ---------------- Kernel 2: MLP on eigenvalues (128 -> 100 -> 100) --------
__global__ __launch_bounds__(128)
void mlp_kernel(const float* __restrict__ e_in,   // [BF][128]
                const float* __restrict__ W0,     // [128][100]
                const float* __restrict__ b0,
                const float* __restrict__ W1,     // [100][100]
                const float* __restrict__ b1,
                float* __restrict__ y_out)        // [BF][100]
{
    __shared__ float ein[128];
    __shared__ float h0[HID];
    const int m = blockIdx.x;
    const int tid = threadIdx.x;
    ein[tid] = e_in[(size_t)m * 128 + tid];
    __syncthreads();
    if (tid < HID) {
        float a = b0[tid];
        for (int i = 0; i < 128; ++i) a += ein[i] * W0[i * HID + tid];
        h0[tid] = fmaxf(a, 0.f);
    }
    __syncthreads();
    if (tid < HID) {
        float a = b1[tid];
        for (int h = 0; h < HID; ++h) a += h0[h] * W1[h * HID + tid];
        y_out[(size_t)m * HID + tid] = fmaxf(a, 0.f);
    }
}

// ---------------- Kernel 3: D = Ysub@W2blk + b2; Out = (D*s)@V^T; exp -----
__global__ __launch_bounds__(256)
void final_kernel(const float* __restrict__ y,     // [BF][100]
                  const float* __restrict__ W2,    // [100][16384]
                  const float* __restrict__ b2,    // [16384]
                  const float* __restrict__ s_in,  // [BF][128]
                  const __half* __restrict__ V_in, // [BF][128 cols][128 k] transposed
                  float* __restrict__ outp)        // [BF][128][128]
{
    extern __shared__ float lds[];
    float* Vs  = lds;            // [128][129] Vs[k][col] (filled in phase 2)
    float* Wm  = lds + 16512;    // [128][129]
    float* Ys  = lds;            // [128][101] staging (overlaps Vs)
    float* W2s = lds + 12928;    // [100][128] staging (overlaps Vs/Wm)

    const int m    = blockIdx.x;
    const int m_hi = m >> 7, m_lo = m & 127;
    const int tid  = threadIdx.x;
    const int tx   = tid & 15, ty = tid >> 4;

    for (int u = tid; u < 128 * 100; u += 256) {
        const int t = u / 100, h = u - t * 100;
        Ys[t * 101 + h] = y[(size_t)(5 * t + m_hi) * 100 + h];
    }
    for (int u = tid; u < 100 * 128; u += 256) {
        const int h = u >> 7, c = u & 127;
        W2s[h * 128 + c] = W2[(size_t)h * 16384 + (size_t)m_lo * 128 + c];
    }
    __syncthreads();

    float acc[8][8];
    #pragma unroll
    for (int a = 0; a < 8; ++a)
        #pragma unroll
        for (int c = 0; c < 8; ++c) acc[a][c] = 0.f;
    for (int h = 0; h < 100; ++h) {
        float yv[8], wv[8];
        #pragma unroll
        for (int a = 0; a < 8; ++a) yv[a] = Ys[(ty + 16 * a) * 101 + h];
        #pragma unroll
        for (int c = 0; c < 8; ++c) wv[c] = W2s[h * 128 + tx + 16 * c];
        #pragma unroll
        for (int a = 0; a < 8; ++a)
            #pragma unroll
            for (int c = 0; c < 8; ++c) acc[a][c] += yv[a] * wv[c];
    }
    {
        float b2v[8], sv[8];
        #pragma unroll
        for (int c = 0; c < 8; ++c) {
            b2v[c] = b2[m_lo * 128 + tx + 16 * c];
            sv[c]  = s_in[(size_t)m * 128 + tx + 16 * c];
        }
        #pragma unroll
        for (int a = 0; a < 8; ++a)
            #pragma unroll
            for (int c = 0; c < 8; ++c)
                acc[a][c] = (acc[a][c] + b2v[c]) * sv[c];
    }
    __syncthreads();

    #pragma unroll
    for (int a = 0; a < 8; ++a)
        #pragma unroll
        for (int c = 0; c < 8; ++c)
            Wm[(ty + 16 * a) * 129 + tx + 16 * c] = acc[a][c];
    for (int u = tid; u < 16384; u += 256) {
        const int colj = u >> 7, k = u & 127;
        Vs[k * 129 + colj] = __half2float(V_in[(size_t)m * 16384 + u]);
    }
    __syncthreads();

    float o[8][8];
    #pragma unroll
    for (int a = 0; a < 8; ++a)
        #pragma unroll
        for (int c = 0; c < 8; ++c) o[a][c] = 0.f;
    for (int j = 0; j < 128; ++j) {
        float wv[8], vv[8];
        #pragma unroll
        for (int a = 0; a < 8; ++a) wv[a] = Wm[(ty + 16 * a) * 129 + j];
        #pragma unroll
        for (int c = 0; c < 8; ++c) vv[c] = Vs[(tx + 16 * c) * 129 + j];
        #pragma unroll
        for (int a = 0; a < 8; ++a)
            #pragma unroll
            for (int c = 0; c < 8; ++c) o[a][c] += wv[a] * vv[c];
    }
    #pragma unroll
    for (int a = 0; a < 8; ++a) {
        const int t = ty + 16 * a;
        const size_t rowbase = (size_t)(5 * t + m_hi) * 16384 + (size_t)m_lo * 128;
        #pragma unroll
        for (int c = 0; c < 8; ++c)
            outp[rowbase + tx + 16 * c] = expf(o[a][c]);
    }
}

// ---------------------------------------------------------------------------
extern "C" void kernel_launch(void* const* d_in, const int* in_sizes, int n_in,
                              void* d_out, int out_size, void* d_ws, size_t ws_size,
                              hipStream_t stream)
{
    const float* Ain = (const float*)d_in[0];
    const float* W0  = (const float*)d_in[1];
    const float* b0  = (const float*)d_in[2];
    const float* W1  = (const float*)d_in[3];
    const float* b1  = (const float*)d_in[4];
    const float* W2  = (const float*)d_in[5];
    const float* b2  = (const float*)d_in[6];
    float* outp = (float*)d_out;

    char* ws = (char*)d_ws;
    __half* Vh  = (__half*)ws;                               // 640*16384*2 = 20971520 B
    float* e_ws = (float*)(ws + 20971520);                   // 640*128*4
    float* s_ws = (float*)(ws + 20971520 + 327680);          // 640*128*4
    float* y_ws = (float*)(ws + 20971520 + 655360);          // 640*100*4

    const size_t lds_bytes = (size_t)(2 * 128 * 129) * sizeof(float); // 132096

    eig_kernel<<<dim3(BF), dim3(512), 0, stream>>>(Ain, e_ws, s_ws, Vh);
    mlp_kernel<<<dim3(BF), dim3(128), 0, stream>>>(e_ws, W0, b0, W1, b1, y_ws);
    final_kernel<<<dim3(BF), dim3(256), lds_bytes, stream>>>(y_ws, W2, b2, s_ws, Vh, outp);
}

// Round 10
// 2773.293 us; speedup vs baseline: 2.7809x; 1.2014x over previous
//
#include <hip/hip_runtime.h>
#include <hip/hip_fp16.h>

#define NSWEEP 12

static constexpr int F_  = 10;
static constexpr int BF  = 640;   // B*F
static constexpr int HID = 100;
static constexpr float MU = 512.0f;   // ~lambda_max of Wishart(128,128)

// ---- DPP helpers ----------------------------------------------------------
template<int CTRL>
__device__ __forceinline__ float dpp_add(float x) {
    int t = __builtin_amdgcn_update_dpp(0, __float_as_int(x), CTRL, 0xF, 0xF, false);
    return x + __int_as_float(t);
}
// 8-lane butterfly all-reduce: xor1, xor2, xor7 — pure VALU, bitwise-uniform.
__device__ __forceinline__ float reduce8(float x) {
    x = dpp_add<0xB1>(x);    // xor 1 (quad_perm [1,0,3,2])
    x = dpp_add<0x4E>(x);    // xor 2 (quad_perm [2,3,0,1])
    x = dpp_add<0x141>(x);   // xor 7 (row_half_mirror)
    return x;
}
// lane-xor data movers: xor8 = DPP row_ror:8 (VALU); xor16/24 = ds_swizzle.
template<int MODE>
__device__ __forceinline__ int mv_i(int x) {
    if constexpr (MODE == 8)
        return __builtin_amdgcn_update_dpp(0, x, 0x128, 0xF, 0xF, false);
    else if constexpr (MODE == 16)
        return __builtin_amdgcn_ds_swizzle(x, 0x401F);
    else
        return __builtin_amdgcn_ds_swizzle(x, 0x601F);
}
template<int MODE>
__device__ __forceinline__ float mv_f(float x) {
    return __int_as_float(mv_i<MODE>(__float_as_int(x)));
}

__device__ __forceinline__ float rcpf(float x) { return __builtin_amdgcn_rcpf(x); }
__device__ __forceinline__ float rsqf(float x) { return __builtin_amdgcn_rsqf(x); }

// Local Jacobi rotation: both columns resident in this lane (16 elems each).
// One instruction stream serves 4 independent pairs (one per 8-lane subgroup).
__device__ __forceinline__ void jrotL(float (&P)[16], float (&Q)[16],
                                      float& np, float& nq) {
    float d0 = 0.f, d1 = 0.f, d2 = 0.f, d3 = 0.f;
    #pragma unroll
    for (int e = 0; e < 4; ++e) {
        d0 = fmaf(P[e],      Q[e],      d0);
        d1 = fmaf(P[e + 4],  Q[e + 4],  d1);
        d2 = fmaf(P[e + 8],  Q[e + 8],  d2);
        d3 = fmaf(P[e + 12], Q[e + 12], d3);
    }
    const float pq = reduce8((d0 + d1) + (d2 + d3));
    if (pq * pq > 1e-28f * np * nq) {
        const float tau = (nq - np) * 0.5f * rcpf(pq);
        const float r   = __builtin_amdgcn_sqrtf(fmaf(tau, tau, 1.f));
        const float t   = rcpf(tau + copysignf(r, tau));
        const float c   = rsqf(fmaf(t, t, 1.f));
        const float s   = t * c;
        #pragma unroll
        for (int e = 0; e < 16; ++e) {
            const float pe = P[e];
            P[e] = fmaf(-s, Q[e], c * pe);
            Q[e] = fmaf(s, pe, c * Q[e]);
        }
        np = fmaf(-t, pq, np);
        nq = fmaf( t, pq, nq);
    }
}

// Cross-subgroup rotation (intra-half-block rounds): partner column fetched
// via lane-xor; each side updates its own column only.
template<int MODE>
__device__ __forceinline__ void jrotX(float (&P)[16], float& np, const bool isp) {
    float part[16];
    #pragma unroll
    for (int e = 0; e < 16; ++e) part[e] = mv_f<MODE>(P[e]);
    const float npart = mv_f<MODE>(np);
    float d0 = 0.f, d1 = 0.f, d2 = 0.f, d3 = 0.f;
    #pragma unroll
    for (int e = 0; e < 4; ++e) {
        d0 = fmaf(P[e],      part[e],      d0);
        d1 = fmaf(P[e + 4],  part[e + 4],  d1);
        d2 = fmaf(P[e + 8],  part[e + 8],  d2);
        d3 = fmaf(P[e + 12], part[e + 12], d3);
    }
    const float pq  = reduce8((d0 + d1) + (d2 + d3));
    const float app = isp ? np : npart;
    const float aqq = isp ? npart : np;
    if (pq * pq > 1e-28f * app * aqq) {
        const float tau = (aqq - app) * 0.5f * rcpf(pq);
        const float r   = __builtin_amdgcn_sqrtf(fmaf(tau, tau, 1.f));
        const float t   = rcpf(tau + copysignf(r, tau));
        const float c   = rsqf(fmaf(t, t, 1.f));
        const float s   = t * c;
        const float sg_ = isp ? -s : s;
        #pragma unroll
        for (int e = 0; e < 16; ++e)
            P[e] = fmaf(sg_, part[e], c * P[e]);
        np = fmaf(isp ? -t : t, pq, np);
    }
}

// ---------------- Kernel 1: Gram(+shift) + block-cyclic one-sided Jacobi ---
// 16 groups x 32 lanes = 64 subgroups of 8; subgroup sg of group g holds the
// pair (T[sg], B[sg]) entirely (16 elems/lane). Cross rounds pair T[sg] with
// B[sg^x] by physically xor-moving B (DPP for xor8, ds_swizzle for xor16/24).
// Half-block movement via 16 aliased LDS slots, 2 phases. Slot layout is
// lane-contiguous [t][sg][l7][4] -> every ds_*_b128 covers 128 consecutive
// words = conflict-free (round-9 lesson: [sg][l7*16] was 16-way conflicted).
__global__ __launch_bounds__(512, 4)
void eig_kernel(const float* __restrict__ Ain,
                float* __restrict__ e_out,          // [BF][128]
                float* __restrict__ s_out,          // [BF][128]
                __half* __restrict__ V_out)         // [BF][128 cols][128 k] (transposed)
{
    __shared__ float SH[16 * 512];   // 16 phys slots (32KB); Gram chunk overlaps
    __shared__ int   exid[31][4];
    __shared__ float key[128], csum[128];
    __shared__ int   idxs[128], rankv[128];

    const int tid = threadIdx.x;
    const int g   = tid >> 5;        // group 0..15
    const int l   = tid & 31;        // lane in group
    const int sg  = l >> 3;          // subgroup 0..3
    const int l7  = l & 7;           // lane in subgroup
    const int e0  = l7 * 16;         // element slice [e0, e0+16)
    const int slw = sg * 32 + l7 * 4;   // lane-contiguous word offset in slot
    const int m   = blockIdx.x;
    const int bb  = m / F_;
    const int ff  = m % F_;

    float T[16], Bc[16];
    float nT, nB;
    int idT = 8 * g + sg;
    int idB = idT + 4;

    // ---- init diag of G = L + MU*I ----
    #pragma unroll
    for (int e = 0; e < 16; ++e) {
        T[e]  = (e0 + e == idT) ? MU : 0.f;
        Bc[e] = (e0 + e == idB) ? MU : 0.f;
    }

    // ---- Gram accumulate in 4 chunks of 32 A-rows ----
    {
        const float* Ab = Ain + (size_t)bb * 128 * 128 * F_ + ff;
        for (int c0 = 0; c0 < 128; c0 += 32) {
            for (int t = tid; t < 4096; t += 512)
                SH[t] = Ab[(size_t)((c0 + (t >> 7)) * 128 + (t & 127)) * F_];
            __syncthreads();
            for (int j = 0; j < 32; ++j) {
                const float at = SH[j * 128 + idT];
                const float ab = SH[j * 128 + idB];
                #pragma unroll
                for (int t = 0; t < 4; ++t) {
                    const float4 a = *(const float4*)&SH[j * 128 + e0 + 4 * t];
                    T[4*t+0]  = fmaf(a.x, at, T[4*t+0]);
                    T[4*t+1]  = fmaf(a.y, at, T[4*t+1]);
                    T[4*t+2]  = fmaf(a.z, at, T[4*t+2]);
                    T[4*t+3]  = fmaf(a.w, at, T[4*t+3]);
                    Bc[4*t+0] = fmaf(a.x, ab, Bc[4*t+0]);
                    Bc[4*t+1] = fmaf(a.y, ab, Bc[4*t+1]);
                    Bc[4*t+2] = fmaf(a.z, ab, Bc[4*t+2]);
                    Bc[4*t+3] = fmaf(a.w, ab, Bc[4*t+3]);
                }
            }
            __syncthreads();
        }
    }

    // exact norms
    {
        float a = 0.f, b = 0.f;
        #pragma unroll
        for (int e = 0; e < 16; ++e) {
            a = fmaf(T[e], T[e], a);
            b = fmaf(Bc[e], Bc[e], b);
        }
        nT = reduce8(a); nB = reduce8(b);
    }

    // ---- sweeps ----
    for (int sw = 0; sw < NSWEEP; ++sw) {
        // intra-half rounds: pairs (sg, sg^r) within T and within B
        {
            const bool p1 = sg < (sg ^ 1), p2 = sg < (sg ^ 2), p3 = sg < (sg ^ 3);
            jrotX<8>(T, nT, p1);   jrotX<8>(Bc, nB, p1);
            jrotX<16>(T, nT, p2);  jrotX<16>(Bc, nB, p2);
            jrotX<24>(T, nT, p3);  jrotX<24>(Bc, nB, p3);
        }

        // 31 co-residencies (circle method on 32 half-blocks, T0 fixed)
        for (int br = 0; br < 31; ++br) {
            // x = 0,1,2,3 pairing via B-moves with deltas xor8,xor24,xor8,xor24
            jrotL(T, Bc, nT, nB);
            #pragma unroll
            for (int e = 0; e < 16; ++e) Bc[e] = mv_f<8>(Bc[e]);
            nB = mv_f<8>(nB); idB = mv_i<8>(idB);
            jrotL(T, Bc, nT, nB);
            #pragma unroll
            for (int e = 0; e < 16; ++e) Bc[e] = mv_f<24>(Bc[e]);
            nB = mv_f<24>(nB); idB = mv_i<24>(idB);
            jrotL(T, Bc, nT, nB);
            #pragma unroll
            for (int e = 0; e < 16; ++e) Bc[e] = mv_f<8>(Bc[e]);
            nB = mv_f<8>(nB); idB = mv_i<8>(idB);
            jrotL(T, Bc, nT, nB);
            #pragma unroll
            for (int e = 0; e < 16; ++e) Bc[e] = mv_f<24>(Bc[e]);   // restore
            nB = mv_f<24>(nB); idB = mv_i<24>(idB);

            // ---- half-block movement, slot cycle T1..T15,B15..B0 -> T1 ----
            // 31 logical slots aliased to 16 phys: s<=14 -> s; 29,30 -> 15;
            // 15..28 -> s-15. Phase 1 = T-chain (+seam B0), phase 2 = B-chain.
            // Slot word layout: [t][sg][l7][4] (lane-contiguous, bank-clean).
            if (g > 0) {                               // T_g -> slot g-1
                float* d = &SH[(g - 1) * 512 + slw];
                #pragma unroll
                for (int t = 0; t < 4; ++t)
                    *(float4*)(d + t * 128) = make_float4(T[4*t], T[4*t+1], T[4*t+2], T[4*t+3]);
                if (l7 == 0) exid[g - 1][sg] = idT;
            } else {                                   // B_0 -> slot 30 (phys 15)
                float* d = &SH[15 * 512 + slw];
                #pragma unroll
                for (int t = 0; t < 4; ++t)
                    *(float4*)(d + t * 128) = make_float4(Bc[4*t], Bc[4*t+1], Bc[4*t+2], Bc[4*t+3]);
                if (l7 == 0) exid[30][sg] = idB;
            }
            __syncthreads();
            if (g >= 1) {                              // T_g <- slot (g==1 ? 30 : g-2)
                const int ph = (g == 1) ? 15 : (g - 2);
                const int sl = (g == 1) ? 30 : (g - 2);
                const float* r = &SH[ph * 512 + slw];
                #pragma unroll
                for (int t = 0; t < 4; ++t) {
                    const float4 v = *(const float4*)(r + t * 128);
                    T[4*t] = v.x; T[4*t+1] = v.y; T[4*t+2] = v.z; T[4*t+3] = v.w;
                }
                idT = exid[sl][sg];
            }
            __syncthreads();
            if (g > 0) {                               // B_g -> slot 30-g (15..29)
                const int s = 30 - g;
                const int ph = (s == 29) ? 15 : (s - 15);
                float* d = &SH[ph * 512 + slw];
                #pragma unroll
                for (int t = 0; t < 4; ++t)
                    *(float4*)(d + t * 128) = make_float4(Bc[4*t], Bc[4*t+1], Bc[4*t+2], Bc[4*t+3]);
                if (l7 == 0) exid[s][sg] = idB;
            }
            __syncthreads();
            {                                          // B_g <- slot 29-g (29..14)
                const int s = 29 - g;
                const int ph = (s == 29) ? 15 : ((s == 14) ? 14 : (s - 15));
                const float* r = &SH[ph * 512 + slw];
                #pragma unroll
                for (int t = 0; t < 4; ++t) {
                    const float4 v = *(const float4*)(r + t * 128);
                    Bc[4*t] = v.x; Bc[4*t+1] = v.y; Bc[4*t+2] = v.z; Bc[4*t+3] = v.w;
                }
                idB = exid[s][sg];
            }
            __syncthreads();
            // exact norm recompute (kills maintained-norm drift)
            {
                float a = 0.f, b = 0.f;
                #pragma unroll
                for (int e = 0; e < 16; ++e) {
                    a = fmaf(T[e], T[e], a);
                    b = fmaf(Bc[e], Bc[e], b);
                }
                nT = reduce8(a); nB = reduce8(b);
            }
        }
    }

    // ---- epilogue ----
    {
        float a = 0.f, ca = 0.f, b = 0.f, cb = 0.f;
        #pragma unroll
        for (int e = 0; e < 16; ++e) {
            a = fmaf(T[e], T[e], a);    ca += T[e];
            b = fmaf(Bc[e], Bc[e], b);  cb += Bc[e];
        }
        a = reduce8(a); ca = reduce8(ca);
        b = reduce8(b); cb = reduce8(cb);
        const float ivT = 1.f / sqrtf(a);
        const float ivB = 1.f / sqrtf(b);
        if (l7 == 0) {
            key[idT] = a;  csum[idT] = ca * ivT * (1.f / 128.f);
            key[idB] = b;  csum[idB] = cb * ivB * (1.f / 128.f);
        }
        __syncthreads();
        if (tid < 128) idxs[tid] = tid;
        __syncthreads();
        for (int kk = 2; kk <= 128; kk <<= 1) {
            for (int jj = kk >> 1; jj > 0; jj >>= 1) {
                if (tid < 128) {
                    const int i = tid, l2 = i ^ jj;
                    if (l2 > i) {
                        const bool up = ((i & kk) == 0);
                        const float ki = key[i], kl = key[l2];
                        if ((ki > kl) == up) {
                            const int ii = idxs[i], il = idxs[l2];
                            key[i] = kl; key[l2] = ki;
                            idxs[i] = il; idxs[l2] = ii;
                        }
                    }
                }
                __syncthreads();
            }
        }
        if (tid < 128) rankv[idxs[tid]] = tid;
        __syncthreads();
        if (tid < 128) {
            e_out[(size_t)m * 128 + tid] = sqrtf(key[tid]) - MU;
            s_out[(size_t)m * 128 + tid] = csum[idxs[tid]];
        }
        __half* Vb = V_out + (size_t)m * 16384;
        const int rkT = rankv[idT], rkB = rankv[idB];
        unsigned int wT[8], wB[8];
        #pragma unroll
        for (int t = 0; t < 8; ++t) {
            __half2 hT = __floats2half2_rn(T[2*t] * ivT,  T[2*t+1] * ivT);
            __half2 hB = __floats2half2_rn(Bc[2*t] * ivB, Bc[2*t+1] * ivB);
            wT[t] = *(unsigned int*)&hT;
            wB[t] = *(unsigned int*)&hB;
        }
        *(uint4*)(Vb + rkT * 128 + e0)     = make_uint4(wT[0], wT[1], wT[2], wT[3]);
        *(uint4*)(Vb + rkT * 128 + e0 + 8) = make_uint4(wT[4], wT[5], wT[6], wT[7]);
        *(uint4*)(Vb + rkB * 128 + e0)     = make_uint4(wB[0], wB[1], wB[2], wB[3]);
        *(uint4*)(Vb + rkB * 128 + e0 + 8) = make_uint4(wB[4], wB[5], wB[6], wB[7]);
    }
}

// ---------------- Kernel 2: MLP on eigenvalues (128 -> 100 -> 100) --------
__global__ __launch_bounds__(128)
void mlp_kernel(const float* __restrict__ e_in,   // [BF][128]
                const float* __restrict__ W0,     // [128][100]
                const float* __restrict__ b0,
                const float* __restrict__ W1,     // [100][100]
                const float* __restrict__ b1,
                float* __restrict__ y_out)        // [BF][100]
{
    __shared__ float ein[128];
    __shared__ float h0[HID];
    const int m = blockIdx.x;
    const int tid = threadIdx.x;
    ein[tid] = e_in[(size_t)m * 128 + tid];
    __syncthreads();
    if (tid < HID) {
        float a = b0[tid];
        for (int i = 0; i < 128; ++i) a += ein[i] * W0[i * HID + tid];
        h0[tid] = fmaxf(a, 0.f);
    }
    __syncthreads();
    if (tid < HID) {
        float a = b1[tid];
        for (int h = 0; h < HID; ++h) a += h0[h] * W1[h * HID + tid];
        y_out[(size_t)m * HID + tid] = fmaxf(a, 0.f);
    }
}

// ---------------- Kernel 3: D = Ysub@W2blk + b2; Out = (D*s)@V^T; exp -----
__global__ __launch_bounds__(256)
void final_kernel(const float* __restrict__ y,     // [BF][100]
                  const float* __restrict__ W2,    // [100][16384]
                  const float* __restrict__ b2,    // [16384]
                  const float* __restrict__ s_in,  // [BF][128]
                  const __half* __restrict__ V_in, // [BF][128 cols][128 k] transposed
                  float* __restrict__ outp)        // [BF][128][128]
{
    extern __shared__ float lds[];
    float* Vs  = lds;            // [128][129] Vs[k][col] (filled in phase 2)
    float* Wm  = lds + 16512;    // [128][129]
    float* Ys  = lds;            // [128][101] staging (overlaps Vs)
    float* W2s = lds + 12928;    // [100][128] staging (overlaps Vs/Wm)

    const int m    = blockIdx.x;
    const int m_hi = m >> 7, m_lo = m & 127;
    const int tid  = threadIdx.x;
    const int tx   = tid & 15, ty = tid >> 4;

    for (int u = tid; u < 128 * 100; u += 256) {
        const int t = u / 100, h = u - t * 100;
        Ys[t * 101 + h] = y[(size_t)(5 * t + m_hi) * 100 + h];
    }
    for (int u = tid; u < 100 * 128; u += 256) {
        const int h = u >> 7, c = u & 127;
        W2s[h * 128 + c] = W2[(size_t)h * 16384 + (size_t)m_lo * 128 + c];
    }
    __syncthreads();

    float acc[8][8];
    #pragma unroll
    for (int a = 0; a < 8; ++a)
        #pragma unroll
        for (int c = 0; c < 8; ++c) acc[a][c] = 0.f;
    for (int h = 0; h < 100; ++h) {
        float yv[8], wv[8];
        #pragma unroll
        for (int a = 0; a < 8; ++a) yv[a] = Ys[(ty + 16 * a) * 101 + h];
        #pragma unroll
        for (int c = 0; c < 8; ++c) wv[c] = W2s[h * 128 + tx + 16 * c];
        #pragma unroll
        for (int a = 0; a < 8; ++a)
            #pragma unroll
            for (int c = 0; c < 8; ++c) acc[a][c] += yv[a] * wv[c];
    }
    {
        float b2v[8], sv[8];
        #pragma unroll
        for (int c = 0; c < 8; ++c) {
            b2v[c] = b2[m_lo * 128 + tx + 16 * c];
            sv[c]  = s_in[(size_t)m * 128 + tx + 16 * c];
        }
        #pragma unroll
        for (int a = 0; a < 8; ++a)
            #pragma unroll
            for (int c = 0; c < 8; ++c)
                acc[a][c] = (acc[a][c] + b2v[c]) * sv[c];
    }
    __syncthreads();

    #pragma unroll
    for (int a = 0; a < 8; ++a)
        #pragma unroll
        for (int c = 0; c < 8; ++c)
            Wm[(ty + 16 * a) * 129 + tx + 16 * c] = acc[a][c];
    for (int u = tid; u < 16384; u += 256) {
        const int colj = u >> 7, k = u & 127;
        Vs[k * 129 + colj] = __half2float(V_in[(size_t)m * 16384 + u]);
    }
    __syncthreads();

    float o[8][8];
    #pragma unroll
    for (int a = 0; a < 8; ++a)
        #pragma unroll
        for (int c = 0; c < 8; ++c) o[a][c] = 0.f;
    for (int j = 0; j < 128; ++j) {
        float wv[8], vv[8];
        #pragma unroll
        for (int a = 0; a < 8; ++a) wv[a] = Wm[(ty + 16 * a) * 129 + j];
        #pragma unroll
        for (int c = 0; c < 8; ++c) vv[c] = Vs[(tx + 16 * c) * 129 + j];
        #pragma unroll
        for (int a = 0; a < 8; ++a)
            #pragma unroll
            for (int c = 0; c < 8; ++c) o[a][c] += wv[a] * vv[c];
    }
    #pragma unroll
    for (int a = 0; a < 8; ++a) {
        const int t = ty + 16 * a;
        const size_t rowbase = (size_t)(5 * t + m_hi) * 16384 + (size_t)m_lo * 128;
        #pragma unroll
        for (int c = 0; c < 8; ++c)
            outp[rowbase + tx + 16 * c] = expf(o[a][c]);
    }
}

// ---------------------------------------------------------------------------
extern "C" void kernel_launch(void* const* d_in, const int* in_sizes, int n_in,
                              void* d_out, int out_size, void* d_ws, size_t ws_size,
                              hipStream_t stream)
{
    const float* Ain = (const float*)d_in[0];
    const float* W0  = (const float*)d_in[1];
    const float* b0  = (const float*)d_in[2];
    const float* W1  = (const float*)d_in[3];
    const float* b1  = (const float*)d_in[4];
    const float* W2  = (const float*)d_in[5];
    const float* b2  = (const float*)d_in[6];
    float* outp = (float*)d_out;

    char* ws = (char*)d_ws;
    __half* Vh  = (__half*)ws;                               // 640*16384*2 = 20971520 B
    float* e_ws = (float*)(ws + 20971520);                   // 640*128*4
    float* s_ws = (float*)(ws + 20971520 + 327680);          // 640*128*4
    float* y_ws = (float*)(ws + 20971520 + 655360);          // 640*100*4

    const size_t lds_bytes = (size_t)(2 * 128 * 129) * sizeof(float); // 132096

    eig_kernel<<<dim3(BF), dim3(512), 0, stream>>>(Ain, e_ws, s_ws, Vh);
    mlp_kernel<<<dim3(BF), dim3(128), 0, stream>>>(e_ws, W0, b0, W1, b1, y_ws);
    final_kernel<<<dim3(BF), dim3(256), lds_bytes, stream>>>(y_ws, W2, b2, s_ws, Vh, outp);
}

// Round 11
// 2292.455 us; speedup vs baseline: 3.3642x; 1.2097x over previous
//
#include <hip/hip_runtime.h>
#include <hip/hip_fp16.h>

#define NSWEEP 12

static constexpr int F_  = 10;
static constexpr int BF  = 640;   // B*F
static constexpr int HID = 100;
static constexpr float MU = 512.0f;   // ~lambda_max of Wishart(128,128)

typedef float f32x2 __attribute__((ext_vector_type(2)));
__device__ __forceinline__ f32x2 pk_fma(f32x2 a, f32x2 b, f32x2 c) {
    return __builtin_elementwise_fma(a, b, c);   // v_pk_fma_f32 on gfx950
}

// ---- DPP helpers ----------------------------------------------------------
template<int CTRL>
__device__ __forceinline__ float dpp_add(float x) {
    int t = __builtin_amdgcn_update_dpp(0, __float_as_int(x), CTRL, 0xF, 0xF, false);
    return x + __int_as_float(t);
}
// 8-lane butterfly all-reduce: xor1, xor2, xor7 — pure VALU, bitwise-uniform.
__device__ __forceinline__ float reduce8(float x) {
    x = dpp_add<0xB1>(x);    // xor 1 (quad_perm [1,0,3,2])
    x = dpp_add<0x4E>(x);    // xor 2 (quad_perm [2,3,0,1])
    x = dpp_add<0x141>(x);   // xor 7 (row_half_mirror)
    return x;
}
// lane-xor data movers: xor8 = DPP row_ror:8 (VALU); xor16/24 = ds_swizzle.
template<int MODE>
__device__ __forceinline__ int mv_i(int x) {
    if constexpr (MODE == 8)
        return __builtin_amdgcn_update_dpp(0, x, 0x128, 0xF, 0xF, false);
    else if constexpr (MODE == 16)
        return __builtin_amdgcn_ds_swizzle(x, 0x401F);
    else
        return __builtin_amdgcn_ds_swizzle(x, 0x601F);
}
template<int MODE>
__device__ __forceinline__ float mv_f(float x) {
    return __int_as_float(mv_i<MODE>(__float_as_int(x)));
}
template<int MODE>
__device__ __forceinline__ void mv_arr(f32x2 (&P)[8]) {
    #pragma unroll
    for (int e = 0; e < 8; ++e) {
        P[e].x = mv_f<MODE>(P[e].x);
        P[e].y = mv_f<MODE>(P[e].y);
    }
}

__device__ __forceinline__ float rcpf(float x) { return __builtin_amdgcn_rcpf(x); }
__device__ __forceinline__ float rsqf(float x) { return __builtin_amdgcn_rsqf(x); }

// packed dot of two 16-elem (8 x f32x2) register arrays -> subgroup scalar
__device__ __forceinline__ float pdot(const f32x2 (&P)[8], const f32x2 (&Q)[8]) {
    f32x2 a0 = P[0] * Q[0], a1 = P[1] * Q[1], a2 = P[2] * Q[2], a3 = P[3] * Q[3];
    a0 = pk_fma(P[4], Q[4], a0);
    a1 = pk_fma(P[5], Q[5], a1);
    a2 = pk_fma(P[6], Q[6], a2);
    a3 = pk_fma(P[7], Q[7], a3);
    const f32x2 r = (a0 + a1) + (a2 + a3);
    return reduce8(r.x + r.y);
}

// Local Jacobi rotation: both columns resident in this lane. One instruction
// stream serves 4 independent pairs (one per 8-lane subgroup).
__device__ __forceinline__ void jrotL(f32x2 (&P)[8], f32x2 (&Q)[8],
                                      float& np, float& nq) {
    const float pq = pdot(P, Q);
    if (pq * pq > 1e-28f * np * nq) {
        const float tau = (nq - np) * 0.5f * rcpf(pq);
        const float r   = __builtin_amdgcn_sqrtf(fmaf(tau, tau, 1.f));
        const float t   = rcpf(tau + copysignf(r, tau));
        const float c   = rsqf(fmaf(t, t, 1.f));
        const float s   = t * c;
        const f32x2 cc = {c, c}, ms = {-s, -s}, ps = {s, s};
        #pragma unroll
        for (int e = 0; e < 8; ++e) {
            const f32x2 pe = P[e];
            P[e] = pk_fma(ms, Q[e], cc * pe);
            Q[e] = pk_fma(ps, pe, cc * Q[e]);
        }
        np = fmaf(-t, pq, np);
        nq = fmaf( t, pq, nq);
    }
}

// Cross-subgroup rotation (intra-half-block rounds): partner fetched via
// lane-xor; each side updates its own column only.
template<int MODE>
__device__ __forceinline__ void jrotX(f32x2 (&P)[8], float& np, const bool isp) {
    f32x2 part[8];
    #pragma unroll
    for (int e = 0; e < 8; ++e) {
        part[e].x = mv_f<MODE>(P[e].x);
        part[e].y = mv_f<MODE>(P[e].y);
    }
    const float npart = mv_f<MODE>(np);
    const float pq  = pdot(P, part);
    const float app = isp ? np : npart;
    const float aqq = isp ? npart : np;
    if (pq * pq > 1e-28f * app * aqq) {
        const float tau = (aqq - app) * 0.5f * rcpf(pq);
        const float r   = __builtin_amdgcn_sqrtf(fmaf(tau, tau, 1.f));
        const float t   = rcpf(tau + copysignf(r, tau));
        const float c   = rsqf(fmaf(t, t, 1.f));
        const float s   = t * c;
        const float sg_ = isp ? -s : s;
        const f32x2 cc = {c, c}, ss = {sg_, sg_};
        #pragma unroll
        for (int e = 0; e < 8; ++e)
            P[e] = pk_fma(ss, part[e], cc * P[e]);
        np = fmaf(isp ? -t : t, pq, np);
    }
}

// ---------------- Kernel 1: Gram(+shift) + block-cyclic one-sided Jacobi ---
// 16 groups x 32 lanes = 64 subgroups of 8; subgroup sg of group g holds a
// (T, B) column pair entirely (16 elems/lane as 8 x f32x2). Cross rounds
// pair T with xor-moved B (no restore move: the resulting B<->subgroup
// permutation is schedule-invariant; ids travel with the data). Half-block
// movement via 16 aliased LDS slots, lane-contiguous [t][sg][l7][4] layout.
__global__ __launch_bounds__(512, 4)
void eig_kernel(const float* __restrict__ Ain,
                float* __restrict__ e_out,          // [BF][128]
                float* __restrict__ s_out,          // [BF][128]
                __half* __restrict__ V_out)         // [BF][128 cols][128 k] (transposed)
{
    __shared__ float SH[16 * 512];   // 16 phys slots (32KB); Gram chunk overlaps
    __shared__ int   exid[31][4];
    __shared__ float key[128], csum[128];
    __shared__ int   idxs[128], rankv[128];

    const int tid = threadIdx.x;
    const int g   = tid >> 5;        // group 0..15
    const int l   = tid & 31;        // lane in group
    const int sg  = l >> 3;          // subgroup 0..3
    const int l7  = l & 7;           // lane in subgroup
    const int e0  = l7 * 16;         // element slice [e0, e0+16)
    const int slw = sg * 32 + l7 * 4;   // lane-contiguous word offset in slot
    const int m   = blockIdx.x;
    const int bb  = m / F_;
    const int ff  = m % F_;

    f32x2 T[8], Bc[8];
    float nT, nB;
    int idT = 8 * g + sg;
    int idB = idT + 4;

    // hoisted movement addresses (loop-invariant)
    float* const wr1   = (g > 0) ? &SH[(g - 1) * 512 + slw] : &SH[15 * 512 + slw];
    const int    wr1s  = (g > 0) ? (g - 1) : 30;
    const float* const rdT  = &SH[((g == 1) ? 15 : (g - 2)) * 512 + slw]; // g>=1
    const int    rdTs  = (g == 1) ? 30 : (g - 2);
    const int    sBw   = 30 - g;
    float* const wrB   = &SH[((sBw == 29) ? 15 : (sBw - 15)) * 512 + slw]; // g>0
    const int    sBr   = 29 - g;
    const float* const rdB =
        &SH[((sBr == 29) ? 15 : ((sBr == 14) ? 14 : (sBr - 15))) * 512 + slw];

    // ---- init diag of G = L + MU*I ----
    #pragma unroll
    for (int e = 0; e < 8; ++e) {
        T[e].x  = (e0 + 2 * e == idT)     ? MU : 0.f;
        T[e].y  = (e0 + 2 * e + 1 == idT) ? MU : 0.f;
        Bc[e].x = (e0 + 2 * e == idB)     ? MU : 0.f;
        Bc[e].y = (e0 + 2 * e + 1 == idB) ? MU : 0.f;
    }

    // ---- Gram accumulate in 4 chunks of 32 A-rows ----
    {
        const float* Ab = Ain + (size_t)bb * 128 * 128 * F_ + ff;
        for (int c0 = 0; c0 < 128; c0 += 32) {
            for (int t = tid; t < 4096; t += 512)
                SH[t] = Ab[(size_t)((c0 + (t >> 7)) * 128 + (t & 127)) * F_];
            __syncthreads();
            for (int j = 0; j < 32; ++j) {
                const float at = SH[j * 128 + idT];
                const float ab = SH[j * 128 + idB];
                const f32x2 at2 = {at, at}, ab2 = {ab, ab};
                #pragma unroll
                for (int t = 0; t < 4; ++t) {
                    const float4 a = *(const float4*)&SH[j * 128 + e0 + 4 * t];
                    const f32x2 lo = {a.x, a.y}, hi = {a.z, a.w};
                    T[2*t]    = pk_fma(lo, at2, T[2*t]);
                    T[2*t+1]  = pk_fma(hi, at2, T[2*t+1]);
                    Bc[2*t]   = pk_fma(lo, ab2, Bc[2*t]);
                    Bc[2*t+1] = pk_fma(hi, ab2, Bc[2*t+1]);
                }
            }
            __syncthreads();
        }
    }

    nT = pdot(T, T);
    nB = pdot(Bc, Bc);

    // ---- sweeps ----
    for (int sw = 0; sw < NSWEEP; ++sw) {
        // intra-half rounds: pairs (sg, sg^r) within T and within B
        {
            const bool p1 = sg < (sg ^ 1), p2 = sg < (sg ^ 2), p3 = sg < (sg ^ 3);
            jrotX<8>(T, nT, p1);   jrotX<8>(Bc, nB, p1);
            jrotX<16>(T, nT, p2);  jrotX<16>(Bc, nB, p2);
            jrotX<24>(T, nT, p3);  jrotX<24>(Bc, nB, p3);
        }

        // 31 co-residencies (circle method on 32 half-blocks, T0 fixed)
        for (int br = 0; br < 31; ++br) {
            // 4 cross-pairings via B lane-xor moves (no restore: permutation
            // of B across subgroups is schedule-invariant, ids travel along)
            jrotL(T, Bc, nT, nB);
            mv_arr<8>(Bc);  nB = mv_f<8>(nB);  idB = mv_i<8>(idB);
            jrotL(T, Bc, nT, nB);
            mv_arr<24>(Bc); nB = mv_f<24>(nB); idB = mv_i<24>(idB);
            jrotL(T, Bc, nT, nB);
            mv_arr<8>(Bc);  nB = mv_f<8>(nB);  idB = mv_i<8>(idB);
            jrotL(T, Bc, nT, nB);

            // ---- half-block movement, slot cycle T1..T15,B15..B0 -> T1 ----
            {   // phase 1: T-chain writes (g>0) / B0 seam write (g==0)
                const f32x2* src = (g > 0) ? T : Bc;
                #pragma unroll
                for (int t = 0; t < 4; ++t)
                    *(float4*)(wr1 + t * 128) =
                        make_float4(src[2*t].x, src[2*t].y, src[2*t+1].x, src[2*t+1].y);
                if (l7 == 0) exid[wr1s][sg] = (g > 0) ? idT : idB;
            }
            __syncthreads();
            if (g >= 1) {
                #pragma unroll
                for (int t = 0; t < 4; ++t) {
                    const float4 v = *(const float4*)(rdT + t * 128);
                    T[2*t]   = f32x2{v.x, v.y};
                    T[2*t+1] = f32x2{v.z, v.w};
                }
                idT = exid[rdTs][sg];
            }
            __syncthreads();
            if (g > 0) {
                #pragma unroll
                for (int t = 0; t < 4; ++t)
                    *(float4*)(wrB + t * 128) =
                        make_float4(Bc[2*t].x, Bc[2*t].y, Bc[2*t+1].x, Bc[2*t+1].y);
                if (l7 == 0) exid[sBw][sg] = idB;
            }
            __syncthreads();
            {
                #pragma unroll
                for (int t = 0; t < 4; ++t) {
                    const float4 v = *(const float4*)(rdB + t * 128);
                    Bc[2*t]   = f32x2{v.x, v.y};
                    Bc[2*t+1] = f32x2{v.z, v.w};
                }
                idB = exid[sBr][sg];
            }
            __syncthreads();
            // exact norm recompute (kills maintained-norm drift)
            nT = pdot(T, T);
            nB = pdot(Bc, Bc);
        }
    }

    // ---- epilogue ----
    {
        float ca = 0.f, cb = 0.f;
        #pragma unroll
        for (int e = 0; e < 8; ++e) {
            ca += T[e].x + T[e].y;
            cb += Bc[e].x + Bc[e].y;
        }
        const float a = pdot(T, T);
        const float b = pdot(Bc, Bc);
        ca = reduce8(ca); cb = reduce8(cb);
        const float ivT = 1.f / sqrtf(a);
        const float ivB = 1.f / sqrtf(b);
        if (l7 == 0) {
            key[idT] = a;  csum[idT] = ca * ivT * (1.f / 128.f);
            key[idB] = b;  csum[idB] = cb * ivB * (1.f / 128.f);
        }
        __syncthreads();
        if (tid < 128) idxs[tid] = tid;
        __syncthreads();
        for (int kk = 2; kk <= 128; kk <<= 1) {
            for (int jj = kk >> 1; jj > 0; jj >>= 1) {
                if (tid < 128) {
                    const int i = tid, l2 = i ^ jj;
                    if (l2 > i) {
                        const bool up = ((i & kk) == 0);
                        const float ki = key[i], kl = key[l2];
                        if ((ki > kl) == up) {
                            const int ii = idxs[i], il = idxs[l2];
                            key[i] = kl; key[l2] = ki;
                            idxs[i] = il; idxs[l2] = ii;
                        }
                    }
                }
                __syncthreads();
            }
        }
        if (tid < 128) rankv[idxs[tid]] = tid;
        __syncthreads();
        if (tid < 128) {
            e_out[(size_t)m * 128 + tid] = sqrtf(key[tid]) - MU;
            s_out[(size_t)m * 128 + tid] = csum[idxs[tid]];
        }
        __half* Vb = V_out + (size_t)m * 16384;
        const int rkT = rankv[idT], rkB = rankv[idB];
        unsigned int wT[8], wB[8];
        #pragma unroll
        for (int t = 0; t < 8; ++t) {
            __half2 hT = __floats2half2_rn(T[t].x * ivT,  T[t].y * ivT);
            __half2 hB = __floats2half2_rn(Bc[t].x * ivB, Bc[t].y * ivB);
            wT[t] = *(unsigned int*)&hT;
            wB[t] = *(unsigned int*)&hB;
        }
        *(uint4*)(Vb + rkT * 128 + e0)     = make_uint4(wT[0], wT[1], wT[2], wT[3]);
        *(uint4*)(Vb + rkT * 128 + e0 + 8) = make_uint4(wT[4], wT[5], wT[6], wT[7]);
        *(uint4*)(Vb + rkB * 128 + e0)     = make_uint4(wB[0], wB[1], wB[2], wB[3]);
        *(uint4*)(Vb + rkB * 128 + e0 + 8) = make_uint4(wB[4], wB[5], wB[6], wB[7]);
    }
}

// ---------------- Kernel 2: MLP on eigenvalues (128 -> 100 -> 100) --------
__global__ __launch_bounds__(128)
void mlp_kernel(const float* __restrict__ e_in,   // [BF][128]
                const float* __restrict__ W0,     // [128][100]
                const float* __restrict__ b0,
                const float* __restrict__ W1,     // [100][100]
                const float* __restrict__ b1,
                float* __restrict__ y_out)        // [BF][100]
{
    __shared__ float ein[128];
    __shared__ float h0[HID];
    const int m = blockIdx.x;
    const int tid = threadIdx.x;
    ein[tid] = e_in[(size_t)m * 128 + tid];
    __syncthreads();
    if (tid < HID) {
        float a = b0[tid];
        for (int i = 0; i < 128; ++i) a += ein[i] * W0[i * HID + tid];
        h0[tid] = fmaxf(a, 0.f);
    }
    __syncthreads();
    if (tid < HID) {
        float a = b1[tid];
        for (int h = 0; h < HID; ++h) a += h0[h] * W1[h * HID + tid];
        y_out[(size_t)m * HID + tid] = fmaxf(a, 0.f);
    }
}

// ---------------- Kernel 3: D = Ysub@W2blk + b2; Out = (D*s)@V^T; exp -----
__global__ __launch_bounds__(256)
void final_kernel(const float* __restrict__ y,     // [BF][100]
                  const float* __restrict__ W2,    // [100][16384]
                  const float* __restrict__ b2,    // [16384]
                  const float* __restrict__ s_in,  // [BF][128]
                  const __half* __restrict__ V_in, // [BF][128 cols][128 k] transposed
                  float* __restrict__ outp)        // [BF][128][128]
{
    extern __shared__ float lds[];
    float* Vs  = lds;            // [128][129] Vs[k][col] (filled in phase 2)
    float* Wm  = lds + 16512;    // [128][129]
    float* Ys  = lds;            // [128][101] staging (overlaps Vs)
    float* W2s = lds + 12928;    // [100][128] staging (overlaps Vs/Wm)

    const int m    = blockIdx.x;
    const int m_hi = m >> 7, m_lo = m & 127;
    const int tid  = threadIdx.x;
    const int tx   = tid & 15, ty = tid >> 4;

    for (int u = tid; u < 128 * 100; u += 256) {
        const int t = u / 100, h = u - t * 100;
        Ys[t * 101 + h] = y[(size_t)(5 * t + m_hi) * 100 + h];
    }
    for (int u = tid; u < 100 * 128; u += 256) {
        const int h = u >> 7, c = u & 127;
        W2s[h * 128 + c] = W2[(size_t)h * 16384 + (size_t)m_lo * 128 + c];
    }
    __syncthreads();

    float acc[8][8];
    #pragma unroll
    for (int a = 0; a < 8; ++a)
        #pragma unroll
        for (int c = 0; c < 8; ++c) acc[a][c] = 0.f;
    for (int h = 0; h < 100; ++h) {
        float yv[8], wv[8];
        #pragma unroll
        for (int a = 0; a < 8; ++a) yv[a] = Ys[(ty + 16 * a) * 101 + h];
        #pragma unroll
        for (int c = 0; c < 8; ++c) wv[c] = W2s[h * 128 + tx + 16 * c];
        #pragma unroll
        for (int a = 0; a < 8; ++a)
            #pragma unroll
            for (int c = 0; c < 8; ++c) acc[a][c] += yv[a] * wv[c];
    }
    {
        float b2v[8], sv[8];
        #pragma unroll
        for (int c = 0; c < 8; ++c) {
            b2v[c] = b2[m_lo * 128 + tx + 16 * c];
            sv[c]  = s_in[(size_t)m * 128 + tx + 16 * c];
        }
        #pragma unroll
        for (int a = 0; a < 8; ++a)
            #pragma unroll
            for (int c = 0; c < 8; ++c)
                acc[a][c] = (acc[a][c] + b2v[c]) * sv[c];
    }
    __syncthreads();

    #pragma unroll
    for (int a = 0; a < 8; ++a)
        #pragma unroll
        for (int c = 0; c < 8; ++c)
            Wm[(ty + 16 * a) * 129 + tx + 16 * c] = acc[a][c];
    for (int u = tid; u < 16384; u += 256) {
        const int colj = u >> 7, k = u & 127;
        Vs[k * 129 + colj] = __half2float(V_in[(size_t)m * 16384 + u]);
    }
    __syncthreads();

    float o[8][8];
    #pragma unroll
    for (int a = 0; a < 8; ++a)
        #pragma unroll
        for (int c = 0; c < 8; ++c) o[a][c] = 0.f;
    for (int j = 0; j < 128; ++j) {
        float wv[8], vv[8];
        #pragma unroll
        for (int a = 0; a < 8; ++a) wv[a] = Wm[(ty + 16 * a) * 129 + j];
        #pragma unroll
        for (int c = 0; c < 8; ++c) vv[c] = Vs[(tx + 16 * c) * 129 + j];
        #pragma unroll
        for (int a = 0; a < 8; ++a)
            #pragma unroll
            for (int c = 0; c < 8; ++c) o[a][c] += wv[a] * vv[c];
    }
    #pragma unroll
    for (int a = 0; a < 8; ++a) {
        const int t = ty + 16 * a;
        const size_t rowbase = (size_t)(5 * t + m_hi) * 16384 + (size_t)m_lo * 128;
        #pragma unroll
        for (int c = 0; c < 8; ++c)
            outp[rowbase + tx + 16 * c] = expf(o[a][c]);
    }
}

// ---------------------------------------------------------------------------
extern "C" void kernel_launch(void* const* d_in, const int* in_sizes, int n_in,
                              void* d_out, int out_size, void* d_ws, size_t ws_size,
                              hipStream_t stream)
{
    const float* Ain = (const float*)d_in[0];
    const float* W0  = (const float*)d_in[1];
    const float* b0  = (const float*)d_in[2];
    const float* W1  = (const float*)d_in[3];
    const float* b1  = (const float*)d_in[4];
    const float* W2  = (const float*)d_in[5];
    const float* b2  = (const float*)d_in[6];
    float* outp = (float*)d_out;

    char* ws = (char*)d_ws;
    __half* Vh  = (__half*)ws;                               // 640*16384*2 = 20971520 B
    float* e_ws = (float*)(ws + 20971520);                   // 640*128*4
    float* s_ws = (float*)(ws + 20971520 + 327680);          // 640*128*4
    float* y_ws = (float*)(ws + 20971520 + 655360);          // 640*100*4

    const size_t lds_bytes = (size_t)(2 * 128 * 129) * sizeof(float); // 132096

    eig_kernel<<<dim3(BF), dim3(512), 0, stream>>>(Ain, e_ws, s_ws, Vh);
    mlp_kernel<<<dim3(BF), dim3(128), 0, stream>>>(e_ws, W0, b0, W1, b1, y_ws);
    final_kernel<<<dim3(BF), dim3(256), lds_bytes, stream>>>(y_ws, W2, b2, s_ws, Vh, outp);
}